// Round 4
// baseline (339.017 us; speedup 1.0000x reference)
//
#include <hip/hip_runtime.h>
#include <math.h>

#define N_NODES 50000
#define N_EDGES 800000
#define HD 256          // NHEAD * OUT_DIM
#define OUT_DIM 64
#define NHEAD 4
#define SLOPE 0.2f
#define BN_EPS 1e-5f
#define LOG2E 1.4426950408889634f
#define NTILES 391      // ceil(N_NODES / 128)
#define NGROUPS 49      // ceil(NTILES / 8)
#define HIST_BLOCKS 96

typedef __attribute__((ext_vector_type(8))) short short8;
typedef __attribute__((ext_vector_type(4))) float float4v;

__device__ __forceinline__ float leaky(float x) { return x >= 0.f ? x : SLOPE * x; }

__device__ __forceinline__ float bf2f(unsigned short u) {
    return __uint_as_float(((unsigned)u) << 16);
}
__device__ __forceinline__ unsigned short f2bf(float f) {
    unsigned u = __float_as_uint(f);
    unsigned r = (u + 0x7fffu + ((u >> 16) & 1u)) >> 16;
    return (unsigned short)r;
}

// 16-lane-group sum via DPP row rotations (pure VALU, no LDS pipe).
template <int CTRL>
__device__ __forceinline__ float ror_add(float v) {
    const int r = __builtin_amdgcn_update_dpp(0, __float_as_int(v), CTRL, 0xF, 0xF, true);
    return v + __int_as_float(r);
}
__device__ __forceinline__ float group16_sum(float v) {
    v = ror_add<0x121>(v);
    v = ror_add<0x122>(v);
    v = ror_add<0x124>(v);
    v = ror_add<0x128>(v);
    return v;
}

// ---------------------------------------------------------------------------
// prep: hist (first 96 blocks, overlaps the streaming cast; cnt pre-zeroed by
// hipMemsetAsync), feat fp32->bf16 cast, 3 weight transpose+casts, zero
// sums/done.
// ---------------------------------------------------------------------------
__global__ __launch_bounds__(256) void prep_kernel(const float* __restrict__ feat,
                                                   const float* __restrict__ W_src,
                                                   const float* __restrict__ W_dst,
                                                   const float* __restrict__ fc_W,
                                                   const int* __restrict__ dst,
                                                   int* __restrict__ cnt,
                                                   unsigned short* __restrict__ feat_bf,
                                                   unsigned short* __restrict__ WtS,
                                                   unsigned short* __restrict__ WtD,
                                                   unsigned short* __restrict__ WtF,
                                                   float* __restrict__ sums,
                                                   int* __restrict__ done) {
    const int b = blockIdx.x;
    const int t = threadIdx.x;
    if (b < HIST_BLOCKS) {
        for (int i = b * 256 + t; i < N_EDGES; i += HIST_BLOCKS * 256)
            atomicAdd(&cnt[dst[i]], 1);
    } else if (b < 12596) {
        const int i = (b - HIST_BLOCKS) * 256 + t;
        const float4 v = ((const float4*)feat)[i];
        ushort4 o;
        o.x = f2bf(v.x); o.y = f2bf(v.y); o.z = f2bf(v.z); o.w = f2bf(v.w);
        ((ushort4*)feat_bf)[i] = o;
    } else if (b < 12852) {
        const int n = b - 12596;
        WtS[(size_t)n * 256 + t] = f2bf(W_src[(size_t)t * 256 + n]);
    } else if (b < 13108) {
        const int n = b - 12852;
        WtD[(size_t)n * 256 + t] = f2bf(W_dst[(size_t)t * 256 + n]);
    } else if (b < 13172) {
        const int n = b - 13108;
        WtF[(size_t)n * 256 + t] = f2bf(fc_W[(size_t)t * 64 + n]);
    } else {
        if (t < 128) sums[t] = 0.f;
        if (t == 128) done[0] = 0;
    }
}

// ---------------------------------------------------------------------------
// bf16 MFMA GEMM, ONE 128-row tile per block, pure (hist moved to prep).
//   jid = blockIdx.x: tile = (jid>>6)*8 + (jid&7), y = (jid>>3)&7
//   (y&3 = 64-col chunk, y>>2 = S/D). A tile's 8 y-variants sit 8 ids apart
//   -> same XCD under round-robin id%8 -> A read once, L2-hit after.
// Epilogue: fragments -> per-wave LDS sub-tile (stride 72 to spread banks)
//   -> row-contiguous readback -> global_store_dwordx4 (full 64B lines).
//   This replaces 32 scalar 2B stores/thread (the invariant that pinned all
//   previous proj versions at ~64 us) with 4 wide stores/thread.
// ---------------------------------------------------------------------------
__global__ __launch_bounds__(256) void proj_kernel(const unsigned short* __restrict__ A,
                                                   const unsigned short* __restrict__ BtS,
                                                   const unsigned short* __restrict__ BtD,
                                                   const float* __restrict__ bS,
                                                   const float* __restrict__ bD,
                                                   unsigned short* __restrict__ CS,
                                                   unsigned short* __restrict__ CD) {
    __shared__ unsigned short Bs[64 * 256];   // 32 KB, fragment-ordered

    const int jid  = blockIdx.x;
    const int tile = (jid >> 6) * 8 + (jid & 7);
    if (tile >= NTILES) return;
    const int yy   = (jid >> 3) & 7;

    const int t    = threadIdx.x;
    const int w    = t >> 6;
    const int lane = t & 63;
    const int q    = lane >> 4;
    const int l16  = lane & 15;
    const int c0   = (yy & 3) * 64;
    const bool isD = (yy >= 4);

    const unsigned short* Bt   = isD ? BtD : BtS;
    const float*          bias = isD ? bD  : bS;
    unsigned short*       C    = isD ? CD  : CS;

    // ---- stage B chunk, fragment order (L2-hot: Wt totals 256 KB) ----
    {
        const int r   = t >> 2;        // B row (= output col) 0..63
        const int seg = t & 3;
        const int c   = r >> 4;
        const int L   = r & 15;
        const unsigned short* g = Bt + (size_t)(c0 + r) * 256 + seg * 64;
#pragma unroll
        for (int kk2 = 0; kk2 < 2; ++kk2) {
            const int kk = seg * 2 + kk2;
#pragma unroll
            for (int q2 = 0; q2 < 4; ++q2)
                *(short8*)(&Bs[((c * 8 + kk) * 64 + q2 * 16 + L) * 8]) =
                    *(const short8*)(g + kk2 * 32 + q2 * 8);
        }
    }
    __syncthreads();

    float vb[4];
#pragma unroll
    for (int c = 0; c < 4; ++c) vb[c] = bias[c0 + c * 16 + l16];

    const int m0 = tile * 128;

    int ar0 = m0 + w * 32 + l16;
    int ar1 = ar0 + 16;
    if (ar0 > N_NODES - 1) ar0 = N_NODES - 1;
    if (ar1 > N_NODES - 1) ar1 = N_NODES - 1;
    const unsigned short* Ab0 = A + (size_t)ar0 * 256 + q * 8;
    const unsigned short* Ab1 = A + (size_t)ar1 * 256 + q * 8;
    short8 afr0[8], afr1[8];
#pragma unroll
    for (int kk = 0; kk < 8; ++kk) {
        afr0[kk] = *(const short8*)(Ab0 + kk * 32);
        afr1[kk] = *(const short8*)(Ab1 + kk * 32);
    }

    float4v a0[4] = {}, a1[4] = {};
#pragma unroll
    for (int kk = 0; kk < 8; ++kk) {
        const short8 af0 = afr0[kk];
        const short8 af1 = afr1[kk];
#pragma unroll
        for (int c = 0; c < 4; ++c) {
            const short8 b = *(const short8*)(&Bs[((c * 8 + kk) * 64 + lane) * 8]);
            a0[c] = __builtin_amdgcn_mfma_f32_16x16x32_bf16(af0, b, a0[c], 0, 0, 0);
            a1[c] = __builtin_amdgcn_mfma_f32_16x16x32_bf16(af1, b, a1[c], 0, 0, 0);
        }
    }

    // ---- transposing epilogue through LDS (reuse Bs; all reads done) ----
    __syncthreads();
    unsigned short* Cw = Bs + w * 2304;        // 32 rows x 64 cols, stride 72
#pragma unroll
    for (int c = 0; c < 4; ++c) {
        const int cl = c * 16 + l16;
#pragma unroll
        for (int i = 0; i < 4; ++i) {
            Cw[(q * 4 + i) * 72 + cl]        = f2bf(a0[c][i] + vb[c]);
            Cw[(q * 4 + i + 16) * 72 + cl]   = f2bf(a1[c][i] + vb[c]);
        }
    }
    // per-wave area: no barrier needed (wave-local lgkmcnt ordering)
#pragma unroll
    for (int j = 0; j < 4; ++j) {
        const int rl = j * 8 + (lane >> 3);    // local row 0..31
        const short8 v = *(const short8*)(Cw + rl * 72 + (lane & 7) * 8);
        const int rg = m0 + w * 32 + rl;
        if (rg < N_NODES)
            *(short8*)(&C[(size_t)rg * 256 + c0 + (lane & 7) * 8]) = v;
    }
}

// ---------------------------------------------------------------------------
// fc GEMM (bf16 MFMA, fp32 out) + fused BatchNorm partial-stats epilogue.
// ---------------------------------------------------------------------------
__global__ __launch_bounds__(256) void fc_bn_kernel(const unsigned short* __restrict__ A,
                                                    const unsigned short* __restrict__ Bt,
                                                    const float* __restrict__ bias,
                                                    float* __restrict__ C,
                                                    float* __restrict__ sums,
                                                    int M) {
    const int w    = threadIdx.x >> 6;
    const int lane = threadIdx.x & 63;
    const int q    = lane >> 4;
    const int l16  = lane & 15;
    const int m0   = blockIdx.x * 64;
    const int t    = threadIdx.x;

    __shared__ float ssum[64], ssq[64];
    if (t < 64) { ssum[t] = 0.f; ssq[t] = 0.f; }

    int arow = m0 + w * 16 + l16;
    if (arow > M - 1) arow = M - 1;
    const unsigned short* Ab  = A  + (size_t)arow * 256 + q * 8;
    const unsigned short* Btb = Bt + (size_t)l16 * 256 + q * 8;

    float4v acc[4] = {};

    for (int k0 = 0; k0 < 256; k0 += 32) {
        const short8 af = *(const short8*)(Ab + k0);
#pragma unroll
        for (int c = 0; c < 4; ++c) {
            const short8 bf = *(const short8*)(Btb + (size_t)c * 16 * 256 + k0);
            acc[c] = __builtin_amdgcn_mfma_f32_16x16x32_bf16(af, bf, acc[c], 0, 0, 0);
        }
    }
    __syncthreads();

#pragma unroll
    for (int c = 0; c < 4; ++c) {
        const int col = c * 16 + l16;
        const float b = bias[col];
        float s = 0.f, qq = 0.f;
#pragma unroll
        for (int i = 0; i < 4; ++i) {
            const int r = m0 + w * 16 + q * 4 + i;
            if (r < M) {
                const float v = acc[c][i] + b;
                C[(size_t)r * 64 + col] = v;
                s += v;
                qq += v * v;
            }
        }
        atomicAdd(&ssum[col], s);
        atomicAdd(&ssq[col], qq);
    }
    __syncthreads();
    if (t < 64) {
        atomicAdd(&sums[t], ssum[t]);
        atomicAdd(&sums[64 + t], ssq[t]);
    }
}

// ---------------------------------------------------------------------------
// CSR build: merged 2-level scan (last-block does chunk-sum scan); scatter.
// (histogram lives inside prep_kernel)
// ---------------------------------------------------------------------------
__global__ __launch_bounds__(512) void scan_kernel(const int* __restrict__ cnt,
                                                   int* __restrict__ offs,
                                                   int* __restrict__ bsum,
                                                   int* __restrict__ bpre,
                                                   int* __restrict__ done) {
    __shared__ int s[512];
    __shared__ bool amLast;
    const int t = threadIdx.x;
    const int i = blockIdx.x * 512 + t;
    const int v = (i < N_NODES) ? cnt[i] : 0;
    s[t] = v;
    __syncthreads();
    for (int off = 1; off < 512; off <<= 1) {
        const int x = (t >= off) ? s[t - off] : 0;
        __syncthreads();
        s[t] += x;
        __syncthreads();
    }
    if (i < N_NODES) offs[i] = s[t] - v;       // exclusive within chunk
    if (t == 511) {
        bsum[blockIdx.x] = s[511];
        __threadfence();
        amLast = (atomicAdd(done, 1) == (int)gridDim.x - 1);
    }
    __syncthreads();
    if (amLast) {
        const int v2 = (t < (int)gridDim.x) ? atomicAdd(&bsum[t], 0) : 0;
        s[t] = v2;
        __syncthreads();
        for (int off = 1; off < 512; off <<= 1) {
            const int x = (t >= off) ? s[t - off] : 0;
            __syncthreads();
            s[t] += x;
            __syncthreads();
        }
        if (t < (int)gridDim.x) bpre[t] = s[t] - v2;
    }
}

__global__ void scatter_kernel(const int* __restrict__ src,
                               const int* __restrict__ dst,
                               const int* __restrict__ offs,
                               const int* __restrict__ bpre,
                               int* __restrict__ cursor,
                               int* __restrict__ srcl) {
    const int i = blockIdx.x * 256 + threadIdx.x;
    if (i < N_EDGES) {
        const int d = dst[i];
        const int p = offs[d] + bpre[d >> 9] + atomicAdd(&cursor[d], 1);
        srcl[p] = src[i];
    }
}

// ---------------------------------------------------------------------------
// Fused GATv2 score + softmax + aggregation: one wave per node. Unroll x4;
// src ids moved to SGPRs via readfirstlane so gathers are saddr-form.
// leaky-dot via 2 FMAs/dim: attn.leaky(y) = c1*y + c2*|y|  (|y| is a free
// VOP3 src modifier), c1 = 0.6*attn*log2e, c2 = 0.4*attn*log2e.
// DPP group reductions; no-max exponentials (|e| << 88; exactly softmax).
// ---------------------------------------------------------------------------
__global__ __launch_bounds__(256) void agg_fused_kernel(const unsigned short* __restrict__ h_src,
                                                        const unsigned short* __restrict__ h_dst,
                                                        const int* __restrict__ srcl,
                                                        const int* __restrict__ offs,
                                                        const int* __restrict__ bpre,
                                                        const float* __restrict__ attn,
                                                        const float* __restrict__ out_bias,
                                                        unsigned short* __restrict__ rst) {
    const int node = blockIdx.x * 4 + (threadIdx.x >> 6);
    const int lane = threadIdx.x & 63;
    const int d4 = lane * 4;

    const int beg = offs[node] + bpre[node >> 9];
    const int end = (node + 1 == N_NODES) ? N_EDGES
                                          : (offs[node + 1] + bpre[(node + 1) >> 9]);

    const uint2 hdu = *(const uint2*)(h_dst + (size_t)node * 256 + d4);
    const float hd0 = __uint_as_float(hdu.x << 16);
    const float hd1 = __uint_as_float(hdu.x & 0xffff0000u);
    const float hd2 = __uint_as_float(hdu.y << 16);
    const float hd3 = __uint_as_float(hdu.y & 0xffff0000u);

    const float4 araw = *(const float4*)(attn + d4);
    const float c10 = araw.x * (0.6f * LOG2E), c20 = araw.x * (0.4f * LOG2E);
    const float c11 = araw.y * (0.6f * LOG2E), c21 = araw.y * (0.4f * LOG2E);
    const float c12 = araw.z * (0.6f * LOG2E), c22 = araw.z * (0.4f * LOG2E);
    const float c13 = araw.w * (0.6f * LOG2E), c23 = araw.w * (0.4f * LOG2E);

    float wsum = 0.f, a0 = 0.f, a1 = 0.f, a2 = 0.f, a3 = 0.f;

    // one edge: returns weight, accumulates
#define EDGE_BODY(sreg)                                                          \
    {                                                                            \
        const unsigned short* row = h_src + (size_t)(sreg) * 256;                \
        const uint2 u = *(const uint2*)(row + d4);                               \
        const float r0 = __uint_as_float(u.x << 16);                             \
        const float r1 = __uint_as_float(u.x & 0xffff0000u);                     \
        const float r2 = __uint_as_float(u.y << 16);                             \
        const float r3 = __uint_as_float(u.y & 0xffff0000u);                     \
        const float y0 = r0 + hd0, y1 = r1 + hd1, y2 = r2 + hd2, y3 = r3 + hd3;  \
        float pp = fmaf(c10, y0, c20 * __builtin_fabsf(y0));                     \
        pp = fmaf(c11, y1, fmaf(c21, __builtin_fabsf(y1), pp));                  \
        pp = fmaf(c12, y2, fmaf(c22, __builtin_fabsf(y2), pp));                  \
        pp = fmaf(c13, y3, fmaf(c23, __builtin_fabsf(y3), pp));                  \
        pp = group16_sum(pp);                                                    \
        const float wg = __builtin_amdgcn_exp2f(pp);                             \
        wsum += wg;                                                              \
        a0 = fmaf(wg, r0, a0);                                                   \
        a1 = fmaf(wg, r1, a1);                                                   \
        a2 = fmaf(wg, r2, a2);                                                   \
        a3 = fmaf(wg, r3, a3);                                                   \
    }

    int p = beg;
    const int nfull = (end - beg) >> 2;
    for (int it = 0; it < nfull; ++it, p += 4) {
        const int s0 = __builtin_amdgcn_readfirstlane(srcl[p]);
        const int s1 = __builtin_amdgcn_readfirstlane(srcl[p + 1]);
        const int s2 = __builtin_amdgcn_readfirstlane(srcl[p + 2]);
        const int s3 = __builtin_amdgcn_readfirstlane(srcl[p + 3]);
        EDGE_BODY(s0);
        EDGE_BODY(s1);
        EDGE_BODY(s2);
        EDGE_BODY(s3);
    }
    for (; p < end; ++p) {
        const int s0 = __builtin_amdgcn_readfirstlane(srcl[p]);
        EDGE_BODY(s0);
    }
#undef EDGE_BODY

    const float inv = (wsum > 0.f) ? 1.f / wsum : 0.f;
    const float4 ob = *(const float4*)(out_bias + d4);
    ushort4 o;
    o.x = f2bf(fmaf(a0, inv, ob.x));
    o.y = f2bf(fmaf(a1, inv, ob.y));
    o.z = f2bf(fmaf(a2, inv, ob.z));
    o.w = f2bf(fmaf(a3, inv, ob.w));
    *(ushort4*)(rst + (size_t)node * 256 + d4) = o;
}

// ---------------------------------------------------------------------------
// BatchNorm finalize + LeakyReLU (float4-vectorized streaming pass)
// ---------------------------------------------------------------------------
__global__ __launch_bounds__(256) void bn_final_kernel(float* __restrict__ z,
                                                       const float* __restrict__ sums,
                                                       const float* __restrict__ gamma,
                                                       const float* __restrict__ beta) {
    const int i = blockIdx.x * 256 + threadIdx.x;    // index of a float4 group
    if (i < N_NODES * 16) {
        const int c4 = (i & 15) * 4;                 // column of first component
        float4 v = ((const float4*)z)[i];
        float out[4] = {v.x, v.y, v.z, v.w};
#pragma unroll
        for (int j = 0; j < 4; ++j) {
            const int col = c4 + j;
            const float mu  = sums[col] * (1.f / N_NODES);
            const float var = sums[64 + col] * (1.f / N_NODES) - mu * mu;
            const float sc  = rsqrtf(var + BN_EPS) * gamma[col];
            const float sh  = beta[col] - mu * sc;
            out[j] = leaky(fmaf(out[j], sc, sh));
        }
        ((float4*)z)[i] = make_float4(out[0], out[1], out[2], out[3]);
    }
}

// ---------------------------------------------------------------------------
extern "C" void kernel_launch(void* const* d_in, const int* in_sizes, int n_in,
                              void* d_out, int out_size, void* d_ws, size_t ws_size,
                              hipStream_t stream) {
    const float* feat    = (const float*)d_in[0];
    const int*   src     = (const int*)  d_in[1];
    const int*   dst     = (const int*)  d_in[2];
    const float* W_src   = (const float*)d_in[3];
    const float* b_src   = (const float*)d_in[4];
    const float* W_dst   = (const float*)d_in[5];
    const float* b_dst   = (const float*)d_in[6];
    const float* attn    = (const float*)d_in[7];
    const float* out_bias= (const float*)d_in[8];
    const float* fc_W    = (const float*)d_in[9];
    const float* fc_b    = (const float*)d_in[10];
    const float* gamma   = (const float*)d_in[11];
    const float* beta    = (const float*)d_in[12];
    float* z = (float*)d_out;

    char* ws = (char*)d_ws;
    size_t off = 0;
    auto carve = [&](size_t bytes) -> void* {
        void* p = ws + off;
        off = (off + bytes + 255) & ~(size_t)255;
        return p;
    };
    unsigned short* feat_bf = (unsigned short*)carve((size_t)N_NODES * 256 * 2);
    unsigned short* h_src_bf= (unsigned short*)carve((size_t)N_NODES * 256 * 2);
    unsigned short* h_dst_bf= (unsigned short*)carve((size_t)N_NODES * 256 * 2);
    unsigned short* rst_bf  = (unsigned short*)carve((size_t)N_NODES * 256 * 2);
    unsigned short* WtS     = (unsigned short*)carve((size_t)256 * 256 * 2);
    unsigned short* WtD     = (unsigned short*)carve((size_t)256 * 256 * 2);
    unsigned short* WtF     = (unsigned short*)carve((size_t)64 * 256 * 2);
    int*   srcl   = (int*)  carve((size_t)N_EDGES * 4);
    int*   cnt    = (int*)  carve((size_t)2 * N_NODES * 4);
    int*   cursor = cnt + N_NODES;
    int*   offs   = (int*)  carve((size_t)(N_NODES + 1) * 4);
    int*   bsum   = (int*)  carve(128 * 4);
    int*   bpre   = (int*)  carve(128 * 4);
    float* sums   = (float*)carve(128 * 4);
    int*   done   = (int*)  carve(64);

    const int nchunks = (N_NODES + 511) / 512;      // 98

    // zero cnt+cursor (graph-capturable), then prep (hist first blocks + cast
    // + transposes + sums/done zero)
    hipMemsetAsync(cnt, 0, (size_t)2 * N_NODES * 4, stream);
    prep_kernel<<<13173, 256, 0, stream>>>(feat, W_src, W_dst, fc_W, dst, cnt,
                                           feat_bf, WtS, WtD, WtF, sums, done);

    // input projections (1 tile/block, XCD-grouped jobs, wide-store epilogue)
    proj_kernel<<<NGROUPS * 64, 256, 0, stream>>>(
        feat_bf, WtS, WtD, b_src, b_dst, h_src_bf, h_dst_bf);

    // CSR by dst (merged scan -> scatter)
    scan_kernel<<<nchunks, 512, 0, stream>>>(cnt, offs, bsum, bpre, done);
    scatter_kernel<<<(N_EDGES + 255) / 256, 256, 0, stream>>>(src, dst, offs, bpre, cursor, srcl);

    // fused score + softmax + aggregation (1 wave per node, DPP reductions)
    agg_fused_kernel<<<N_NODES / 4, 256, 0, stream>>>(h_src_bf, h_dst_bf, srcl, offs, bpre,
                                                      attn, out_bias, rst_bf);

    // trailing fc + BN partial stats
    fc_bn_kernel<<<(N_NODES + 63) / 64, 256, 0, stream>>>(rst_bf, WtF, fc_b, z, sums, N_NODES);

    // batchnorm finalize + leaky (vectorized)
    bn_final_kernel<<<(N_NODES * 16 + 255) / 256, 256, 0, stream>>>(z, sums, gamma, beta);
}

// Round 5
// 325.340 us; speedup vs baseline: 1.0420x; 1.0420x over previous
//
#include <hip/hip_runtime.h>
#include <math.h>

#define N_NODES 50000
#define N_EDGES 800000
#define HD 256          // NHEAD * OUT_DIM
#define OUT_DIM 64
#define NHEAD 4
#define SLOPE 0.2f
#define BN_EPS 1e-5f
#define LOG2E 1.4426950408889634f
#define NTILES 391      // ceil(N_NODES / 128)
#define NGROUPS 49      // ceil(NTILES / 8)
#define HIST_BLOCKS 96

typedef __attribute__((ext_vector_type(8))) short short8;
typedef __attribute__((ext_vector_type(4))) float float4v;

__device__ __forceinline__ float leaky(float x) { return x >= 0.f ? x : SLOPE * x; }

__device__ __forceinline__ float bf2f(unsigned short u) {
    return __uint_as_float(((unsigned)u) << 16);
}
__device__ __forceinline__ unsigned short f2bf(float f) {
    unsigned u = __float_as_uint(f);
    unsigned r = (u + 0x7fffu + ((u >> 16) & 1u)) >> 16;
    return (unsigned short)r;
}

// 16-lane-group sum via DPP row rotations (builtin form, used on tail path).
template <int CTRL>
__device__ __forceinline__ float ror_add(float v) {
    const int r = __builtin_amdgcn_update_dpp(0, __float_as_int(v), CTRL, 0xF, 0xF, true);
    return v + __int_as_float(r);
}
__device__ __forceinline__ float group16_sum(float v) {
    v = ror_add<0x121>(v);
    v = ror_add<0x122>(v);
    v = ror_add<0x124>(v);
    v = ror_add<0x128>(v);
    return v;
}

// 4 interleaved 16-lane reductions with FUSED v_add_f32_dpp (half the issue
// slots of mov_dpp+add). Chains interleaved -> >=3 instrs between dependent
// DPPs; s_nop 1 covers the VALU-write -> DPP-read entry hazard.
__device__ __forceinline__ void group16_sum4(float& v0, float& v1, float& v2, float& v3) {
    asm volatile(
        "s_nop 1\n\t"
        "v_add_f32_dpp %0, %0, %0 row_ror:1 row_mask:0xf bank_mask:0xf\n\t"
        "v_add_f32_dpp %1, %1, %1 row_ror:1 row_mask:0xf bank_mask:0xf\n\t"
        "v_add_f32_dpp %2, %2, %2 row_ror:1 row_mask:0xf bank_mask:0xf\n\t"
        "v_add_f32_dpp %3, %3, %3 row_ror:1 row_mask:0xf bank_mask:0xf\n\t"
        "v_add_f32_dpp %0, %0, %0 row_ror:2 row_mask:0xf bank_mask:0xf\n\t"
        "v_add_f32_dpp %1, %1, %1 row_ror:2 row_mask:0xf bank_mask:0xf\n\t"
        "v_add_f32_dpp %2, %2, %2 row_ror:2 row_mask:0xf bank_mask:0xf\n\t"
        "v_add_f32_dpp %3, %3, %3 row_ror:2 row_mask:0xf bank_mask:0xf\n\t"
        "v_add_f32_dpp %0, %0, %0 row_ror:4 row_mask:0xf bank_mask:0xf\n\t"
        "v_add_f32_dpp %1, %1, %1 row_ror:4 row_mask:0xf bank_mask:0xf\n\t"
        "v_add_f32_dpp %2, %2, %2 row_ror:4 row_mask:0xf bank_mask:0xf\n\t"
        "v_add_f32_dpp %3, %3, %3 row_ror:4 row_mask:0xf bank_mask:0xf\n\t"
        "v_add_f32_dpp %0, %0, %0 row_ror:8 row_mask:0xf bank_mask:0xf\n\t"
        "v_add_f32_dpp %1, %1, %1 row_ror:8 row_mask:0xf bank_mask:0xf\n\t"
        "v_add_f32_dpp %2, %2, %2 row_ror:8 row_mask:0xf bank_mask:0xf\n\t"
        "v_add_f32_dpp %3, %3, %3 row_ror:8 row_mask:0xf bank_mask:0xf"
        : "+v"(v0), "+v"(v1), "+v"(v2), "+v"(v3));
}

// ---------------------------------------------------------------------------
// prep: feat fp32->bf16 cast, 3 weight transpose+casts, zero cnt/cursor/sums/
// done (r3 arrangement: hist lives in proj, no memset).
// ---------------------------------------------------------------------------
__global__ __launch_bounds__(256) void prep_kernel(const float* __restrict__ feat,
                                                   const float* __restrict__ W_src,
                                                   const float* __restrict__ W_dst,
                                                   const float* __restrict__ fc_W,
                                                   unsigned short* __restrict__ feat_bf,
                                                   unsigned short* __restrict__ WtS,
                                                   unsigned short* __restrict__ WtD,
                                                   unsigned short* __restrict__ WtF,
                                                   int* __restrict__ cnt2,
                                                   float* __restrict__ sums,
                                                   int* __restrict__ done) {
    const int b = blockIdx.x;
    const int t = threadIdx.x;
    if (b < 12500) {
        const int i = b * 256 + t;
        const float4 v = ((const float4*)feat)[i];
        ushort4 o;
        o.x = f2bf(v.x); o.y = f2bf(v.y); o.z = f2bf(v.z); o.w = f2bf(v.w);
        ((ushort4*)feat_bf)[i] = o;
    } else if (b < 12756) {
        const int n = b - 12500;
        WtS[(size_t)n * 256 + t] = f2bf(W_src[(size_t)t * 256 + n]);
    } else if (b < 13012) {
        const int n = b - 12756;
        WtD[(size_t)n * 256 + t] = f2bf(W_dst[(size_t)t * 256 + n]);
    } else if (b < 13076) {
        const int n = b - 13012;
        WtF[(size_t)n * 256 + t] = f2bf(fc_W[(size_t)t * 64 + n]);
    } else if (b < 13174) {
        const int i = (b - 13076) * 256 + t;
        if (i < 25000) ((int4*)cnt2)[i] = make_int4(0, 0, 0, 0);
    } else {
        if (t < 128) sums[t] = 0.f;
        if (t == 128) done[0] = 0;
    }
}

// ---------------------------------------------------------------------------
// bf16 MFMA GEMM, ONE 128-row tile per block, + fused edge histogram.
// Blocks [0,96): histogram (overlaps GEMM). jid = id-96:
//   tile = (jid>>6)*8 + (jid&7), y = (jid>>3)&7 (y&3 = col chunk, y>>2 = S/D);
//   a tile's 8 y-variants sit 8 ids apart -> same XCD -> A L2-hit reuse.
// B staged in LDS with XOR swizzle idx ^= ((c8kk>>1)&3)<<4 (shorts) on BOTH
//   write and read: kills the 4-way ds_write_b128 phase conflict (r3: 2.4M
//   conflict cycles) while keeping reads conflict-free (keys are unroll-
//   constant -> free).
// Epilogue: fragments -> per-wave LDS sub-tile -> short8 readback ->
//   global_store_dwordx4 full-line stores.
// ---------------------------------------------------------------------------
__global__ __launch_bounds__(256) void proj_kernel(const unsigned short* __restrict__ A,
                                                   const unsigned short* __restrict__ BtS,
                                                   const unsigned short* __restrict__ BtD,
                                                   const float* __restrict__ bS,
                                                   const float* __restrict__ bD,
                                                   unsigned short* __restrict__ CS,
                                                   unsigned short* __restrict__ CD,
                                                   const int* __restrict__ dst,
                                                   int* __restrict__ cnt) {
    __shared__ unsigned short Bs[64 * 256];   // 32 KB

    if (blockIdx.x < HIST_BLOCKS) {
        for (int i = blockIdx.x * 256 + threadIdx.x; i < N_EDGES; i += HIST_BLOCKS * 256)
            atomicAdd(&cnt[dst[i]], 1);
        return;
    }

    const int jid  = blockIdx.x - HIST_BLOCKS;
    const int tile = (jid >> 6) * 8 + (jid & 7);
    if (tile >= NTILES) return;
    const int yy   = (jid >> 3) & 7;

    const int t    = threadIdx.x;
    const int w    = t >> 6;
    const int lane = t & 63;
    const int q    = lane >> 4;
    const int l16  = lane & 15;
    const int c0   = (yy & 3) * 64;
    const bool isD = (yy >= 4);

    const unsigned short* Bt   = isD ? BtD : BtS;
    const float*          bias = isD ? bD  : bS;
    unsigned short*       C    = isD ? CD  : CS;

    // ---- stage B chunk, fragment order, XOR-swizzled ----
    {
        const int r   = t >> 2;        // B row (= output col) 0..63
        const int seg = t & 3;
        const int c   = r >> 4;
        const int L   = r & 15;
        const unsigned short* g = Bt + (size_t)(c0 + r) * 256 + seg * 64;
#pragma unroll
        for (int kk2 = 0; kk2 < 2; ++kk2) {
            const int kk   = seg * 2 + kk2;
            const int c8kk = c * 8 + kk;
            const int key  = ((c8kk >> 1) & 3) << 4;
#pragma unroll
            for (int q2 = 0; q2 < 4; ++q2)
                *(short8*)(&Bs[((c8kk * 64 + q2 * 16 + L) * 8) ^ key]) =
                    *(const short8*)(g + kk2 * 32 + q2 * 8);
        }
    }
    __syncthreads();

    float vb[4];
#pragma unroll
    for (int c = 0; c < 4; ++c) vb[c] = bias[c0 + c * 16 + l16];

    const int m0 = tile * 128;

    int ar0 = m0 + w * 32 + l16;
    int ar1 = ar0 + 16;
    if (ar0 > N_NODES - 1) ar0 = N_NODES - 1;
    if (ar1 > N_NODES - 1) ar1 = N_NODES - 1;
    const unsigned short* Ab0 = A + (size_t)ar0 * 256 + q * 8;
    const unsigned short* Ab1 = A + (size_t)ar1 * 256 + q * 8;
    short8 afr0[8], afr1[8];
#pragma unroll
    for (int kk = 0; kk < 8; ++kk) {
        afr0[kk] = *(const short8*)(Ab0 + kk * 32);
        afr1[kk] = *(const short8*)(Ab1 + kk * 32);
    }

    const int la8 = lane * 8;
    const int lsw[4] = {la8, la8 ^ 16, la8 ^ 32, la8 ^ 48};

    float4v a0[4] = {}, a1[4] = {};
#pragma unroll
    for (int kk = 0; kk < 8; ++kk) {
        const short8 af0 = afr0[kk];
        const short8 af1 = afr1[kk];
#pragma unroll
        for (int c = 0; c < 4; ++c) {
            const int c8kk = c * 8 + kk;
            const short8 b = *(const short8*)(&Bs[c8kk * 512 + lsw[(c8kk >> 1) & 3]]);
            a0[c] = __builtin_amdgcn_mfma_f32_16x16x32_bf16(af0, b, a0[c], 0, 0, 0);
            a1[c] = __builtin_amdgcn_mfma_f32_16x16x32_bf16(af1, b, a1[c], 0, 0, 0);
        }
    }

    // ---- transposing epilogue through LDS (reuse Bs; all reads done) ----
    __syncthreads();
    unsigned short* Cw = Bs + w * 2304;        // 32 rows x 64 cols, stride 72
#pragma unroll
    for (int c = 0; c < 4; ++c) {
        const int cl = c * 16 + l16;
#pragma unroll
        for (int i = 0; i < 4; ++i) {
            Cw[(q * 4 + i) * 72 + cl]        = f2bf(a0[c][i] + vb[c]);
            Cw[(q * 4 + i + 16) * 72 + cl]   = f2bf(a1[c][i] + vb[c]);
        }
    }
    // per-wave area: no barrier needed (wave-local lgkmcnt ordering)
#pragma unroll
    for (int j = 0; j < 4; ++j) {
        const int rl = j * 8 + (lane >> 3);    // local row 0..31
        const short8 v = *(const short8*)(Cw + rl * 72 + (lane & 7) * 8);
        const int rg = m0 + w * 32 + rl;
        if (rg < N_NODES)
            *(short8*)(&C[(size_t)rg * 256 + c0 + (lane & 7) * 8]) = v;
    }
}

// ---------------------------------------------------------------------------
// fc GEMM (bf16 MFMA, fp32 out) + fused BatchNorm partial-stats epilogue.
// ---------------------------------------------------------------------------
__global__ __launch_bounds__(256) void fc_bn_kernel(const unsigned short* __restrict__ A,
                                                    const unsigned short* __restrict__ Bt,
                                                    const float* __restrict__ bias,
                                                    float* __restrict__ C,
                                                    float* __restrict__ sums,
                                                    int M) {
    const int w    = threadIdx.x >> 6;
    const int lane = threadIdx.x & 63;
    const int q    = lane >> 4;
    const int l16  = lane & 15;
    const int m0   = blockIdx.x * 64;
    const int t    = threadIdx.x;

    __shared__ float ssum[64], ssq[64];
    if (t < 64) { ssum[t] = 0.f; ssq[t] = 0.f; }

    int arow = m0 + w * 16 + l16;
    if (arow > M - 1) arow = M - 1;
    const unsigned short* Ab  = A  + (size_t)arow * 256 + q * 8;
    const unsigned short* Btb = Bt + (size_t)l16 * 256 + q * 8;

    float4v acc[4] = {};

    for (int k0 = 0; k0 < 256; k0 += 32) {
        const short8 af = *(const short8*)(Ab + k0);
#pragma unroll
        for (int c = 0; c < 4; ++c) {
            const short8 bf = *(const short8*)(Btb + (size_t)c * 16 * 256 + k0);
            acc[c] = __builtin_amdgcn_mfma_f32_16x16x32_bf16(af, bf, acc[c], 0, 0, 0);
        }
    }
    __syncthreads();

#pragma unroll
    for (int c = 0; c < 4; ++c) {
        const int col = c * 16 + l16;
        const float b = bias[col];
        float s = 0.f, qq = 0.f;
#pragma unroll
        for (int i = 0; i < 4; ++i) {
            const int r = m0 + w * 16 + q * 4 + i;
            if (r < M) {
                const float v = acc[c][i] + b;
                C[(size_t)r * 64 + col] = v;
                s += v;
                qq += v * v;
            }
        }
        atomicAdd(&ssum[col], s);
        atomicAdd(&ssq[col], qq);
    }
    __syncthreads();
    if (t < 64) {
        atomicAdd(&sums[t], ssum[t]);
        atomicAdd(&sums[64 + t], ssq[t]);
    }
}

// ---------------------------------------------------------------------------
// CSR build: merged 2-level scan (last-block does chunk-sum scan); scatter.
// ---------------------------------------------------------------------------
__global__ __launch_bounds__(512) void scan_kernel(const int* __restrict__ cnt,
                                                   int* __restrict__ offs,
                                                   int* __restrict__ bsum,
                                                   int* __restrict__ bpre,
                                                   int* __restrict__ done) {
    __shared__ int s[512];
    __shared__ bool amLast;
    const int t = threadIdx.x;
    const int i = blockIdx.x * 512 + t;
    const int v = (i < N_NODES) ? cnt[i] : 0;
    s[t] = v;
    __syncthreads();
    for (int off = 1; off < 512; off <<= 1) {
        const int x = (t >= off) ? s[t - off] : 0;
        __syncthreads();
        s[t] += x;
        __syncthreads();
    }
    if (i < N_NODES) offs[i] = s[t] - v;       // exclusive within chunk
    if (t == 511) {
        bsum[blockIdx.x] = s[511];
        __threadfence();
        amLast = (atomicAdd(done, 1) == (int)gridDim.x - 1);
    }
    __syncthreads();
    if (amLast) {
        const int v2 = (t < (int)gridDim.x) ? atomicAdd(&bsum[t], 0) : 0;
        s[t] = v2;
        __syncthreads();
        for (int off = 1; off < 512; off <<= 1) {
            const int x = (t >= off) ? s[t - off] : 0;
            __syncthreads();
            s[t] += x;
            __syncthreads();
        }
        if (t < (int)gridDim.x) bpre[t] = s[t] - v2;
    }
}

__global__ void scatter_kernel(const int* __restrict__ src,
                               const int* __restrict__ dst,
                               const int* __restrict__ offs,
                               const int* __restrict__ bpre,
                               int* __restrict__ cursor,
                               int* __restrict__ srcl) {
    const int i = blockIdx.x * 256 + threadIdx.x;
    if (i < N_EDGES) {
        const int d = dst[i];
        const int p = offs[d] + bpre[d >> 9] + atomicAdd(&cursor[d], 1);
        srcl[p] = src[i];
    }
}

// ---------------------------------------------------------------------------
// Fused GATv2 score + softmax + aggregation: one wave per node, 512-thread
// blocks (8 nodes) for occupancy. 4-edge batches with phases: (A) issue all
// loads, (B) dots, (C) 4 interleaved FUSED-DPP reductions, (D) exp+accum.
// leaky-dot via 2 FMAs/dim using the free |y| VOP3 modifier.
// ---------------------------------------------------------------------------
__global__ __launch_bounds__(512) void agg_fused_kernel(const unsigned short* __restrict__ h_src,
                                                        const unsigned short* __restrict__ h_dst,
                                                        const int* __restrict__ srcl,
                                                        const int* __restrict__ offs,
                                                        const int* __restrict__ bpre,
                                                        const float* __restrict__ attn,
                                                        const float* __restrict__ out_bias,
                                                        unsigned short* __restrict__ rst) {
    const int node = blockIdx.x * 8 + (threadIdx.x >> 6);
    const int lane = threadIdx.x & 63;
    const int d4 = lane * 4;

    const int beg = offs[node] + bpre[node >> 9];
    const int end = (node + 1 == N_NODES) ? N_EDGES
                                          : (offs[node + 1] + bpre[(node + 1) >> 9]);

    const uint2 hdu = *(const uint2*)(h_dst + (size_t)node * 256 + d4);
    const float hd0 = __uint_as_float(hdu.x << 16);
    const float hd1 = __uint_as_float(hdu.x & 0xffff0000u);
    const float hd2 = __uint_as_float(hdu.y << 16);
    const float hd3 = __uint_as_float(hdu.y & 0xffff0000u);

    const float4 araw = *(const float4*)(attn + d4);
    const float c10 = araw.x * (0.6f * LOG2E), c20 = araw.x * (0.4f * LOG2E);
    const float c11 = araw.y * (0.6f * LOG2E), c21 = araw.y * (0.4f * LOG2E);
    const float c12 = araw.z * (0.6f * LOG2E), c22 = araw.z * (0.4f * LOG2E);
    const float c13 = araw.w * (0.6f * LOG2E), c23 = araw.w * (0.4f * LOG2E);

    float wsum = 0.f, a0 = 0.f, a1 = 0.f, a2 = 0.f, a3 = 0.f;

#define DOT_PP(u, r0, r1, r2, r3, pp)                                            \
    const float r0 = __uint_as_float(u.x << 16);                                 \
    const float r1 = __uint_as_float(u.x & 0xffff0000u);                         \
    const float r2 = __uint_as_float(u.y << 16);                                 \
    const float r3 = __uint_as_float(u.y & 0xffff0000u);                         \
    float pp;                                                                    \
    {                                                                            \
        const float y0 = r0 + hd0, y1 = r1 + hd1, y2 = r2 + hd2, y3 = r3 + hd3;  \
        pp = fmaf(c10, y0, c20 * __builtin_fabsf(y0));                           \
        pp = fmaf(c11, y1, fmaf(c21, __builtin_fabsf(y1), pp));                  \
        pp = fmaf(c12, y2, fmaf(c22, __builtin_fabsf(y2), pp));                  \
        pp = fmaf(c13, y3, fmaf(c23, __builtin_fabsf(y3), pp));                  \
    }

    int p = beg;
    const int nfull = (end - beg) >> 2;
    for (int it = 0; it < nfull; ++it, p += 4) {
        const int s0 = __builtin_amdgcn_readfirstlane(srcl[p]);
        const int s1 = __builtin_amdgcn_readfirstlane(srcl[p + 1]);
        const int s2 = __builtin_amdgcn_readfirstlane(srcl[p + 2]);
        const int s3 = __builtin_amdgcn_readfirstlane(srcl[p + 3]);
        // phase A: issue all four gathers
        const uint2 u0 = *(const uint2*)(h_src + (size_t)s0 * 256 + d4);
        const uint2 u1 = *(const uint2*)(h_src + (size_t)s1 * 256 + d4);
        const uint2 u2 = *(const uint2*)(h_src + (size_t)s2 * 256 + d4);
        const uint2 u3 = *(const uint2*)(h_src + (size_t)s3 * 256 + d4);
        // phase B: per-edge dots
        DOT_PP(u0, r00, r01, r02, r03, pp0)
        DOT_PP(u1, r10, r11, r12, r13, pp1)
        DOT_PP(u2, r20, r21, r22, r23, pp2)
        DOT_PP(u3, r30, r31, r32, r33, pp3)
        // phase C: 4 interleaved fused-DPP 16-lane reductions
        group16_sum4(pp0, pp1, pp2, pp3);
        // phase D: exponentials + accumulation
        const float wg0 = __builtin_amdgcn_exp2f(pp0);
        const float wg1 = __builtin_amdgcn_exp2f(pp1);
        const float wg2 = __builtin_amdgcn_exp2f(pp2);
        const float wg3 = __builtin_amdgcn_exp2f(pp3);
        wsum += (wg0 + wg1) + (wg2 + wg3);
        a0 = fmaf(wg0, r00, fmaf(wg1, r10, fmaf(wg2, r20, fmaf(wg3, r30, a0))));
        a1 = fmaf(wg0, r01, fmaf(wg1, r11, fmaf(wg2, r21, fmaf(wg3, r31, a1))));
        a2 = fmaf(wg0, r02, fmaf(wg1, r12, fmaf(wg2, r22, fmaf(wg3, r32, a2))));
        a3 = fmaf(wg0, r03, fmaf(wg1, r13, fmaf(wg2, r23, fmaf(wg3, r33, a3))));
    }
    for (; p < end; ++p) {
        const int s0 = __builtin_amdgcn_readfirstlane(srcl[p]);
        const uint2 u0 = *(const uint2*)(h_src + (size_t)s0 * 256 + d4);
        DOT_PP(u0, r00, r01, r02, r03, pp0)
        pp0 = group16_sum(pp0);
        const float wg = __builtin_amdgcn_exp2f(pp0);
        wsum += wg;
        a0 = fmaf(wg, r00, a0);
        a1 = fmaf(wg, r01, a1);
        a2 = fmaf(wg, r02, a2);
        a3 = fmaf(wg, r03, a3);
    }
#undef DOT_PP

    const float inv = (wsum > 0.f) ? 1.f / wsum : 0.f;
    const float4 ob = *(const float4*)(out_bias + d4);
    ushort4 o;
    o.x = f2bf(fmaf(a0, inv, ob.x));
    o.y = f2bf(fmaf(a1, inv, ob.y));
    o.z = f2bf(fmaf(a2, inv, ob.z));
    o.w = f2bf(fmaf(a3, inv, ob.w));
    *(ushort4*)(rst + (size_t)node * 256 + d4) = o;
}

// ---------------------------------------------------------------------------
// BatchNorm finalize + LeakyReLU (float4-vectorized streaming pass)
// ---------------------------------------------------------------------------
__global__ __launch_bounds__(256) void bn_final_kernel(float* __restrict__ z,
                                                       const float* __restrict__ sums,
                                                       const float* __restrict__ gamma,
                                                       const float* __restrict__ beta) {
    const int i = blockIdx.x * 256 + threadIdx.x;    // index of a float4 group
    if (i < N_NODES * 16) {
        const int c4 = (i & 15) * 4;                 // column of first component
        float4 v = ((const float4*)z)[i];
        float out[4] = {v.x, v.y, v.z, v.w};
#pragma unroll
        for (int j = 0; j < 4; ++j) {
            const int col = c4 + j;
            const float mu  = sums[col] * (1.f / N_NODES);
            const float var = sums[64 + col] * (1.f / N_NODES) - mu * mu;
            const float sc  = rsqrtf(var + BN_EPS) * gamma[col];
            const float sh  = beta[col] - mu * sc;
            out[j] = leaky(fmaf(out[j], sc, sh));
        }
        ((float4*)z)[i] = make_float4(out[0], out[1], out[2], out[3]);
    }
}

// ---------------------------------------------------------------------------
extern "C" void kernel_launch(void* const* d_in, const int* in_sizes, int n_in,
                              void* d_out, int out_size, void* d_ws, size_t ws_size,
                              hipStream_t stream) {
    const float* feat    = (const float*)d_in[0];
    const int*   src     = (const int*)  d_in[1];
    const int*   dst     = (const int*)  d_in[2];
    const float* W_src   = (const float*)d_in[3];
    const float* b_src   = (const float*)d_in[4];
    const float* W_dst   = (const float*)d_in[5];
    const float* b_dst   = (const float*)d_in[6];
    const float* attn    = (const float*)d_in[7];
    const float* out_bias= (const float*)d_in[8];
    const float* fc_W    = (const float*)d_in[9];
    const float* fc_b    = (const float*)d_in[10];
    const float* gamma   = (const float*)d_in[11];
    const float* beta    = (const float*)d_in[12];
    float* z = (float*)d_out;

    char* ws = (char*)d_ws;
    size_t off = 0;
    auto carve = [&](size_t bytes) -> void* {
        void* p = ws + off;
        off = (off + bytes + 255) & ~(size_t)255;
        return p;
    };
    unsigned short* feat_bf = (unsigned short*)carve((size_t)N_NODES * 256 * 2);
    unsigned short* h_src_bf= (unsigned short*)carve((size_t)N_NODES * 256 * 2);
    unsigned short* h_dst_bf= (unsigned short*)carve((size_t)N_NODES * 256 * 2);
    unsigned short* rst_bf  = (unsigned short*)carve((size_t)N_NODES * 256 * 2);
    unsigned short* WtS     = (unsigned short*)carve((size_t)256 * 256 * 2);
    unsigned short* WtD     = (unsigned short*)carve((size_t)256 * 256 * 2);
    unsigned short* WtF     = (unsigned short*)carve((size_t)64 * 256 * 2);
    int*   srcl   = (int*)  carve((size_t)N_EDGES * 4);
    int*   cnt    = (int*)  carve((size_t)2 * N_NODES * 4);
    int*   cursor = cnt + N_NODES;
    int*   offs   = (int*)  carve((size_t)(N_NODES + 1) * 4);
    int*   bsum   = (int*)  carve(128 * 4);
    int*   bpre   = (int*)  carve(128 * 4);
    float* sums   = (float*)carve(128 * 4);
    int*   done   = (int*)  carve(64);

    const int nchunks = (N_NODES + 511) / 512;      // 98

    // prep: cast + transposes + zeroing
    prep_kernel<<<13175, 256, 0, stream>>>(feat, W_src, W_dst, fc_W,
                                           feat_bf, WtS, WtD, WtF, cnt, sums, done);

    // input projections (1 tile/block, XCD-grouped jobs, swizzled LDS,
    // wide-store epilogue) + fused histogram
    proj_kernel<<<HIST_BLOCKS + NGROUPS * 64, 256, 0, stream>>>(
        feat_bf, WtS, WtD, b_src, b_dst, h_src_bf, h_dst_bf, dst, cnt);

    // CSR by dst (merged scan -> scatter)
    scan_kernel<<<nchunks, 512, 0, stream>>>(cnt, offs, bsum, bpre, done);
    scatter_kernel<<<(N_EDGES + 255) / 256, 256, 0, stream>>>(src, dst, offs, bpre, cursor, srcl);

    // fused score + softmax + aggregation (1 wave/node, 8 nodes/block)
    agg_fused_kernel<<<N_NODES / 8, 512, 0, stream>>>(h_src_bf, h_dst_bf, srcl, offs, bpre,
                                                      attn, out_bias, rst_bf);

    // trailing fc + BN partial stats
    fc_bn_kernel<<<(N_NODES + 63) / 64, 256, 0, stream>>>(rst_bf, WtF, fc_b, z, sums, N_NODES);

    // batchnorm finalize + leaky (vectorized)
    bn_final_kernel<<<(N_NODES * 16 + 255) / 256, 256, 0, stream>>>(z, sums, gamma, beta);
}

// Round 6
// 320.001 us; speedup vs baseline: 1.0594x; 1.0167x over previous
//
#include <hip/hip_runtime.h>
#include <math.h>

#define N_NODES 50000
#define N_EDGES 800000
#define HD 256          // NHEAD * OUT_DIM
#define OUT_DIM 64
#define NHEAD 4
#define SLOPE 0.2f
#define BN_EPS 1e-5f
#define LOG2E 1.4426950408889634f
#define NTILES 391      // ceil(N_NODES / 128)
#define NGROUPS 49      // ceil(NTILES / 8)
#define HIST_BLOCKS 96

typedef __attribute__((ext_vector_type(8))) short short8;
typedef __attribute__((ext_vector_type(4))) float float4v;

__device__ __forceinline__ float leaky(float x) { return x >= 0.f ? x : SLOPE * x; }

__device__ __forceinline__ float bf2f(unsigned short u) {
    return __uint_as_float(((unsigned)u) << 16);
}
__device__ __forceinline__ unsigned short f2bf(float f) {
    unsigned u = __float_as_uint(f);
    unsigned r = (u + 0x7fffu + ((u >> 16) & 1u)) >> 16;
    return (unsigned short)r;
}

// 16-lane-group sum via DPP row rotations (pure VALU, no LDS pipe).
// Builtin form: the compiler interleaves these chains across unrolled edges,
// which beats a hand-fused asm block (r5 regression: asm wall -> stalls).
template <int CTRL>
__device__ __forceinline__ float ror_add(float v) {
    const int r = __builtin_amdgcn_update_dpp(0, __float_as_int(v), CTRL, 0xF, 0xF, true);
    return v + __int_as_float(r);
}
__device__ __forceinline__ float group16_sum(float v) {
    v = ror_add<0x121>(v);
    v = ror_add<0x122>(v);
    v = ror_add<0x124>(v);
    v = ror_add<0x128>(v);
    return v;
}

// ---------------------------------------------------------------------------
// prep: feat fp32->bf16 cast, 3 weight transpose+casts, zero cnt/cursor/sums/
// done (hist lives in proj; no memset).
// ---------------------------------------------------------------------------
__global__ __launch_bounds__(256) void prep_kernel(const float* __restrict__ feat,
                                                   const float* __restrict__ W_src,
                                                   const float* __restrict__ W_dst,
                                                   const float* __restrict__ fc_W,
                                                   unsigned short* __restrict__ feat_bf,
                                                   unsigned short* __restrict__ WtS,
                                                   unsigned short* __restrict__ WtD,
                                                   unsigned short* __restrict__ WtF,
                                                   int* __restrict__ cnt2,
                                                   float* __restrict__ sums,
                                                   int* __restrict__ done) {
    const int b = blockIdx.x;
    const int t = threadIdx.x;
    if (b < 12500) {
        const int i = b * 256 + t;
        const float4 v = ((const float4*)feat)[i];
        ushort4 o;
        o.x = f2bf(v.x); o.y = f2bf(v.y); o.z = f2bf(v.z); o.w = f2bf(v.w);
        ((ushort4*)feat_bf)[i] = o;
    } else if (b < 12756) {
        const int n = b - 12500;
        WtS[(size_t)n * 256 + t] = f2bf(W_src[(size_t)t * 256 + n]);
    } else if (b < 13012) {
        const int n = b - 12756;
        WtD[(size_t)n * 256 + t] = f2bf(W_dst[(size_t)t * 256 + n]);
    } else if (b < 13076) {
        const int n = b - 13012;
        WtF[(size_t)n * 256 + t] = f2bf(fc_W[(size_t)t * 64 + n]);
    } else if (b < 13174) {
        const int i = (b - 13076) * 256 + t;
        if (i < 25000) ((int4*)cnt2)[i] = make_int4(0, 0, 0, 0);
    } else {
        if (t < 128) sums[t] = 0.f;
        if (t == 128) done[0] = 0;
    }
}

// ---------------------------------------------------------------------------
// bf16 MFMA GEMM, ONE 128-row tile per block, + fused edge histogram.
// Blocks [0,96): histogram (overlaps GEMM). jid = id-96:
//   tile = (jid>>6)*8 + (jid&7), y = (jid>>3)&7 (y&3 = col chunk, y>>2 = S/D);
//   a tile's 8 y-variants sit 8 ids apart -> same XCD -> A L2-hit reuse.
// B staged in LDS with XOR swizzle idx ^= ((c8kk>>1)&3)<<4 (shorts) on BOTH
//   write and read: kills the 4-way ds_write_b128 phase conflict.
// Epilogue: fragments -> per-wave LDS sub-tile -> short8 readback ->
//   global_store_dwordx4 full-line stores.
// ---------------------------------------------------------------------------
__global__ __launch_bounds__(256) void proj_kernel(const unsigned short* __restrict__ A,
                                                   const unsigned short* __restrict__ BtS,
                                                   const unsigned short* __restrict__ BtD,
                                                   const float* __restrict__ bS,
                                                   const float* __restrict__ bD,
                                                   unsigned short* __restrict__ CS,
                                                   unsigned short* __restrict__ CD,
                                                   const int* __restrict__ dst,
                                                   int* __restrict__ cnt) {
    __shared__ unsigned short Bs[64 * 256];   // 32 KB

    if (blockIdx.x < HIST_BLOCKS) {
        for (int i = blockIdx.x * 256 + threadIdx.x; i < N_EDGES; i += HIST_BLOCKS * 256)
            atomicAdd(&cnt[dst[i]], 1);
        return;
    }

    const int jid  = blockIdx.x - HIST_BLOCKS;
    const int tile = (jid >> 6) * 8 + (jid & 7);
    if (tile >= NTILES) return;
    const int yy   = (jid >> 3) & 7;

    const int t    = threadIdx.x;
    const int w    = t >> 6;
    const int lane = t & 63;
    const int q    = lane >> 4;
    const int l16  = lane & 15;
    const int c0   = (yy & 3) * 64;
    const bool isD = (yy >= 4);

    const unsigned short* Bt   = isD ? BtD : BtS;
    const float*          bias = isD ? bD  : bS;
    unsigned short*       C    = isD ? CD  : CS;

    // ---- stage B chunk, fragment order, XOR-swizzled ----
    {
        const int r   = t >> 2;        // B row (= output col) 0..63
        const int seg = t & 3;
        const int c   = r >> 4;
        const int L   = r & 15;
        const unsigned short* g = Bt + (size_t)(c0 + r) * 256 + seg * 64;
#pragma unroll
        for (int kk2 = 0; kk2 < 2; ++kk2) {
            const int kk   = seg * 2 + kk2;
            const int c8kk = c * 8 + kk;
            const int key  = ((c8kk >> 1) & 3) << 4;
#pragma unroll
            for (int q2 = 0; q2 < 4; ++q2)
                *(short8*)(&Bs[((c8kk * 64 + q2 * 16 + L) * 8) ^ key]) =
                    *(const short8*)(g + kk2 * 32 + q2 * 8);
        }
    }
    __syncthreads();

    float vb[4];
#pragma unroll
    for (int c = 0; c < 4; ++c) vb[c] = bias[c0 + c * 16 + l16];

    const int m0 = tile * 128;

    int ar0 = m0 + w * 32 + l16;
    int ar1 = ar0 + 16;
    if (ar0 > N_NODES - 1) ar0 = N_NODES - 1;
    if (ar1 > N_NODES - 1) ar1 = N_NODES - 1;
    const unsigned short* Ab0 = A + (size_t)ar0 * 256 + q * 8;
    const unsigned short* Ab1 = A + (size_t)ar1 * 256 + q * 8;
    short8 afr0[8], afr1[8];
#pragma unroll
    for (int kk = 0; kk < 8; ++kk) {
        afr0[kk] = *(const short8*)(Ab0 + kk * 32);
        afr1[kk] = *(const short8*)(Ab1 + kk * 32);
    }

    const int la8 = lane * 8;
    const int lsw[4] = {la8, la8 ^ 16, la8 ^ 32, la8 ^ 48};

    float4v a0[4] = {}, a1[4] = {};
#pragma unroll
    for (int kk = 0; kk < 8; ++kk) {
        const short8 af0 = afr0[kk];
        const short8 af1 = afr1[kk];
#pragma unroll
        for (int c = 0; c < 4; ++c) {
            const int c8kk = c * 8 + kk;
            const short8 b = *(const short8*)(&Bs[c8kk * 512 + lsw[(c8kk >> 1) & 3]]);
            a0[c] = __builtin_amdgcn_mfma_f32_16x16x32_bf16(af0, b, a0[c], 0, 0, 0);
            a1[c] = __builtin_amdgcn_mfma_f32_16x16x32_bf16(af1, b, a1[c], 0, 0, 0);
        }
    }

    // ---- transposing epilogue through LDS (reuse Bs; all reads done) ----
    __syncthreads();
    unsigned short* Cw = Bs + w * 2304;        // 32 rows x 64 cols, stride 72
#pragma unroll
    for (int c = 0; c < 4; ++c) {
        const int cl = c * 16 + l16;
#pragma unroll
        for (int i = 0; i < 4; ++i) {
            Cw[(q * 4 + i) * 72 + cl]        = f2bf(a0[c][i] + vb[c]);
            Cw[(q * 4 + i + 16) * 72 + cl]   = f2bf(a1[c][i] + vb[c]);
        }
    }
    // per-wave area: no barrier needed (wave-local lgkmcnt ordering)
#pragma unroll
    for (int j = 0; j < 4; ++j) {
        const int rl = j * 8 + (lane >> 3);    // local row 0..31
        const short8 v = *(const short8*)(Cw + rl * 72 + (lane & 7) * 8);
        const int rg = m0 + w * 32 + rl;
        if (rg < N_NODES)
            *(short8*)(&C[(size_t)rg * 256 + c0 + (lane & 7) * 8]) = v;
    }
}

// ---------------------------------------------------------------------------
// fc GEMM (bf16 MFMA, fp32 out) + fused BatchNorm partial-stats epilogue.
// ---------------------------------------------------------------------------
__global__ __launch_bounds__(256) void fc_bn_kernel(const unsigned short* __restrict__ A,
                                                    const unsigned short* __restrict__ Bt,
                                                    const float* __restrict__ bias,
                                                    float* __restrict__ C,
                                                    float* __restrict__ sums,
                                                    int M) {
    const int w    = threadIdx.x >> 6;
    const int lane = threadIdx.x & 63;
    const int q    = lane >> 4;
    const int l16  = lane & 15;
    const int m0   = blockIdx.x * 64;
    const int t    = threadIdx.x;

    __shared__ float ssum[64], ssq[64];
    if (t < 64) { ssum[t] = 0.f; ssq[t] = 0.f; }

    int arow = m0 + w * 16 + l16;
    if (arow > M - 1) arow = M - 1;
    const unsigned short* Ab  = A  + (size_t)arow * 256 + q * 8;
    const unsigned short* Btb = Bt + (size_t)l16 * 256 + q * 8;

    float4v acc[4] = {};

    for (int k0 = 0; k0 < 256; k0 += 32) {
        const short8 af = *(const short8*)(Ab + k0);
#pragma unroll
        for (int c = 0; c < 4; ++c) {
            const short8 bf = *(const short8*)(Btb + (size_t)c * 16 * 256 + k0);
            acc[c] = __builtin_amdgcn_mfma_f32_16x16x32_bf16(af, bf, acc[c], 0, 0, 0);
        }
    }
    __syncthreads();

#pragma unroll
    for (int c = 0; c < 4; ++c) {
        const int col = c * 16 + l16;
        const float b = bias[col];
        float s = 0.f, qq = 0.f;
#pragma unroll
        for (int i = 0; i < 4; ++i) {
            const int r = m0 + w * 16 + q * 4 + i;
            if (r < M) {
                const float v = acc[c][i] + b;
                C[(size_t)r * 64 + col] = v;
                s += v;
                qq += v * v;
            }
        }
        atomicAdd(&ssum[col], s);
        atomicAdd(&ssq[col], qq);
    }
    __syncthreads();
    if (t < 64) {
        atomicAdd(&sums[t], ssum[t]);
        atomicAdd(&sums[64 + t], ssq[t]);
    }
}

// ---------------------------------------------------------------------------
// CSR build: merged 2-level scan (last-block does chunk-sum scan); scatter.
// ---------------------------------------------------------------------------
__global__ __launch_bounds__(512) void scan_kernel(const int* __restrict__ cnt,
                                                   int* __restrict__ offs,
                                                   int* __restrict__ bsum,
                                                   int* __restrict__ bpre,
                                                   int* __restrict__ done) {
    __shared__ int s[512];
    __shared__ bool amLast;
    const int t = threadIdx.x;
    const int i = blockIdx.x * 512 + t;
    const int v = (i < N_NODES) ? cnt[i] : 0;
    s[t] = v;
    __syncthreads();
    for (int off = 1; off < 512; off <<= 1) {
        const int x = (t >= off) ? s[t - off] : 0;
        __syncthreads();
        s[t] += x;
        __syncthreads();
    }
    if (i < N_NODES) offs[i] = s[t] - v;       // exclusive within chunk
    if (t == 511) {
        bsum[blockIdx.x] = s[511];
        __threadfence();
        amLast = (atomicAdd(done, 1) == (int)gridDim.x - 1);
    }
    __syncthreads();
    if (amLast) {
        const int v2 = (t < (int)gridDim.x) ? atomicAdd(&bsum[t], 0) : 0;
        s[t] = v2;
        __syncthreads();
        for (int off = 1; off < 512; off <<= 1) {
            const int x = (t >= off) ? s[t - off] : 0;
            __syncthreads();
            s[t] += x;
            __syncthreads();
        }
        if (t < (int)gridDim.x) bpre[t] = s[t] - v2;
    }
}

__global__ void scatter_kernel(const int* __restrict__ src,
                               const int* __restrict__ dst,
                               const int* __restrict__ offs,
                               const int* __restrict__ bpre,
                               int* __restrict__ cursor,
                               int* __restrict__ srcl) {
    const int i = blockIdx.x * 256 + threadIdx.x;
    if (i < N_EDGES) {
        const int d = dst[i];
        const int p = offs[d] + bpre[d >> 9] + atomicAdd(&cursor[d], 1);
        srcl[p] = src[i];
    }
}

// ---------------------------------------------------------------------------
// Fused GATv2 score + softmax + aggregation: one wave per node, 4 nodes per
// 256-thread block (r3-verified configuration: 64.0-64.6 us). Unroll x4;
// src ids moved to SGPRs via readfirstlane so gathers are saddr-form.
// leaky-dot via 2 FMAs/dim: attn.leaky(y) = c1*y + c2*|y|  (|y| is a free
// VOP3 src modifier). DPP group reductions (builtin; compiler-scheduled).
// No-max exponentials (|e| << 88; exactly softmax).
// ---------------------------------------------------------------------------
__global__ __launch_bounds__(256) void agg_fused_kernel(const unsigned short* __restrict__ h_src,
                                                        const unsigned short* __restrict__ h_dst,
                                                        const int* __restrict__ srcl,
                                                        const int* __restrict__ offs,
                                                        const int* __restrict__ bpre,
                                                        const float* __restrict__ attn,
                                                        const float* __restrict__ out_bias,
                                                        unsigned short* __restrict__ rst) {
    const int node = blockIdx.x * 4 + (threadIdx.x >> 6);
    const int lane = threadIdx.x & 63;
    const int d4 = lane * 4;

    const int beg = offs[node] + bpre[node >> 9];
    const int end = (node + 1 == N_NODES) ? N_EDGES
                                          : (offs[node + 1] + bpre[(node + 1) >> 9]);

    const uint2 hdu = *(const uint2*)(h_dst + (size_t)node * 256 + d4);
    const float hd0 = __uint_as_float(hdu.x << 16);
    const float hd1 = __uint_as_float(hdu.x & 0xffff0000u);
    const float hd2 = __uint_as_float(hdu.y << 16);
    const float hd3 = __uint_as_float(hdu.y & 0xffff0000u);

    const float4 araw = *(const float4*)(attn + d4);
    const float c10 = araw.x * (0.6f * LOG2E), c20 = araw.x * (0.4f * LOG2E);
    const float c11 = araw.y * (0.6f * LOG2E), c21 = araw.y * (0.4f * LOG2E);
    const float c12 = araw.z * (0.6f * LOG2E), c22 = araw.z * (0.4f * LOG2E);
    const float c13 = araw.w * (0.6f * LOG2E), c23 = araw.w * (0.4f * LOG2E);

    float wsum = 0.f, a0 = 0.f, a1 = 0.f, a2 = 0.f, a3 = 0.f;

    // one edge: returns weight, accumulates
#define EDGE_BODY(sreg)                                                          \
    {                                                                            \
        const unsigned short* row = h_src + (size_t)(sreg) * 256;                \
        const uint2 u = *(const uint2*)(row + d4);                               \
        const float r0 = __uint_as_float(u.x << 16);                             \
        const float r1 = __uint_as_float(u.x & 0xffff0000u);                     \
        const float r2 = __uint_as_float(u.y << 16);                             \
        const float r3 = __uint_as_float(u.y & 0xffff0000u);                     \
        const float y0 = r0 + hd0, y1 = r1 + hd1, y2 = r2 + hd2, y3 = r3 + hd3;  \
        float pp = fmaf(c10, y0, c20 * __builtin_fabsf(y0));                     \
        pp = fmaf(c11, y1, fmaf(c21, __builtin_fabsf(y1), pp));                  \
        pp = fmaf(c12, y2, fmaf(c22, __builtin_fabsf(y2), pp));                  \
        pp = fmaf(c13, y3, fmaf(c23, __builtin_fabsf(y3), pp));                  \
        pp = group16_sum(pp);                                                    \
        const float wg = __builtin_amdgcn_exp2f(pp);                             \
        wsum += wg;                                                              \
        a0 = fmaf(wg, r0, a0);                                                   \
        a1 = fmaf(wg, r1, a1);                                                   \
        a2 = fmaf(wg, r2, a2);                                                   \
        a3 = fmaf(wg, r3, a3);                                                   \
    }

    int p = beg;
    const int nfull = (end - beg) >> 2;
    for (int it = 0; it < nfull; ++it, p += 4) {
        const int s0 = __builtin_amdgcn_readfirstlane(srcl[p]);
        const int s1 = __builtin_amdgcn_readfirstlane(srcl[p + 1]);
        const int s2 = __builtin_amdgcn_readfirstlane(srcl[p + 2]);
        const int s3 = __builtin_amdgcn_readfirstlane(srcl[p + 3]);
        EDGE_BODY(s0);
        EDGE_BODY(s1);
        EDGE_BODY(s2);
        EDGE_BODY(s3);
    }
    for (; p < end; ++p) {
        const int s0 = __builtin_amdgcn_readfirstlane(srcl[p]);
        EDGE_BODY(s0);
    }
#undef EDGE_BODY

    const float inv = (wsum > 0.f) ? 1.f / wsum : 0.f;
    const float4 ob = *(const float4*)(out_bias + d4);
    ushort4 o;
    o.x = f2bf(fmaf(a0, inv, ob.x));
    o.y = f2bf(fmaf(a1, inv, ob.y));
    o.z = f2bf(fmaf(a2, inv, ob.z));
    o.w = f2bf(fmaf(a3, inv, ob.w));
    *(ushort4*)(rst + (size_t)node * 256 + d4) = o;
}

// ---------------------------------------------------------------------------
// BatchNorm finalize + LeakyReLU (float4-vectorized streaming pass)
// ---------------------------------------------------------------------------
__global__ __launch_bounds__(256) void bn_final_kernel(float* __restrict__ z,
                                                       const float* __restrict__ sums,
                                                       const float* __restrict__ gamma,
                                                       const float* __restrict__ beta) {
    const int i = blockIdx.x * 256 + threadIdx.x;    // index of a float4 group
    if (i < N_NODES * 16) {
        const int c4 = (i & 15) * 4;                 // column of first component
        float4 v = ((const float4*)z)[i];
        float out[4] = {v.x, v.y, v.z, v.w};
#pragma unroll
        for (int j = 0; j < 4; ++j) {
            const int col = c4 + j;
            const float mu  = sums[col] * (1.f / N_NODES);
            const float var = sums[64 + col] * (1.f / N_NODES) - mu * mu;
            const float sc  = rsqrtf(var + BN_EPS) * gamma[col];
            const float sh  = beta[col] - mu * sc;
            out[j] = leaky(fmaf(out[j], sc, sh));
        }
        ((float4*)z)[i] = make_float4(out[0], out[1], out[2], out[3]);
    }
}

// ---------------------------------------------------------------------------
extern "C" void kernel_launch(void* const* d_in, const int* in_sizes, int n_in,
                              void* d_out, int out_size, void* d_ws, size_t ws_size,
                              hipStream_t stream) {
    const float* feat    = (const float*)d_in[0];
    const int*   src     = (const int*)  d_in[1];
    const int*   dst     = (const int*)  d_in[2];
    const float* W_src   = (const float*)d_in[3];
    const float* b_src   = (const float*)d_in[4];
    const float* W_dst   = (const float*)d_in[5];
    const float* b_dst   = (const float*)d_in[6];
    const float* attn    = (const float*)d_in[7];
    const float* out_bias= (const float*)d_in[8];
    const float* fc_W    = (const float*)d_in[9];
    const float* fc_b    = (const float*)d_in[10];
    const float* gamma   = (const float*)d_in[11];
    const float* beta    = (const float*)d_in[12];
    float* z = (float*)d_out;

    char* ws = (char*)d_ws;
    size_t off = 0;
    auto carve = [&](size_t bytes) -> void* {
        void* p = ws + off;
        off = (off + bytes + 255) & ~(size_t)255;
        return p;
    };
    unsigned short* feat_bf = (unsigned short*)carve((size_t)N_NODES * 256 * 2);
    unsigned short* h_src_bf= (unsigned short*)carve((size_t)N_NODES * 256 * 2);
    unsigned short* h_dst_bf= (unsigned short*)carve((size_t)N_NODES * 256 * 2);
    unsigned short* rst_bf  = (unsigned short*)carve((size_t)N_NODES * 256 * 2);
    unsigned short* WtS     = (unsigned short*)carve((size_t)256 * 256 * 2);
    unsigned short* WtD     = (unsigned short*)carve((size_t)256 * 256 * 2);
    unsigned short* WtF     = (unsigned short*)carve((size_t)64 * 256 * 2);
    int*   srcl   = (int*)  carve((size_t)N_EDGES * 4);
    int*   cnt    = (int*)  carve((size_t)2 * N_NODES * 4);
    int*   cursor = cnt + N_NODES;
    int*   offs   = (int*)  carve((size_t)(N_NODES + 1) * 4);
    int*   bsum   = (int*)  carve(128 * 4);
    int*   bpre   = (int*)  carve(128 * 4);
    float* sums   = (float*)carve(128 * 4);
    int*   done   = (int*)  carve(64);

    const int nchunks = (N_NODES + 511) / 512;      // 98

    // prep: cast + transposes + zeroing
    prep_kernel<<<13175, 256, 0, stream>>>(feat, W_src, W_dst, fc_W,
                                           feat_bf, WtS, WtD, WtF, cnt, sums, done);

    // input projections (1 tile/block, XCD-grouped jobs, swizzled LDS,
    // wide-store epilogue) + fused histogram
    proj_kernel<<<HIST_BLOCKS + NGROUPS * 64, 256, 0, stream>>>(
        feat_bf, WtS, WtD, b_src, b_dst, h_src_bf, h_dst_bf, dst, cnt);

    // CSR by dst (merged scan -> scatter)
    scan_kernel<<<nchunks, 512, 0, stream>>>(cnt, offs, bsum, bpre, done);
    scatter_kernel<<<(N_EDGES + 255) / 256, 256, 0, stream>>>(src, dst, offs, bpre, cursor, srcl);

    // fused score + softmax + aggregation (1 wave per node, DPP reductions)
    agg_fused_kernel<<<N_NODES / 4, 256, 0, stream>>>(h_src_bf, h_dst_bf, srcl, offs, bpre,
                                                      attn, out_bias, rst_bf);

    // trailing fc + BN partial stats
    fc_bn_kernel<<<(N_NODES + 63) / 64, 256, 0, stream>>>(rst_bf, WtF, fc_b, z, sums, N_NODES);

    // batchnorm finalize + leaky (vectorized)
    bn_final_kernel<<<(N_NODES * 16 + 255) / 256, 256, 0, stream>>>(z, sums, gamma, beta);
}

// Round 7
// 311.799 us; speedup vs baseline: 1.0873x; 1.0263x over previous
//
#include <hip/hip_runtime.h>
#include <math.h>

#define N_NODES 50000
#define N_EDGES 800000
#define HD 256          // NHEAD * OUT_DIM
#define OUT_DIM 64
#define NHEAD 4
#define SLOPE 0.2f
#define BN_EPS 1e-5f
#define LOG2E 1.4426950408889634f
#define NTILES 391      // ceil(N_NODES / 128)
#define NGROUPS 49      // ceil(NTILES / 8)
#define HIST_BLOCKS 96

typedef __attribute__((ext_vector_type(8))) short short8;
typedef __attribute__((ext_vector_type(4))) float float4v;

__device__ __forceinline__ float leaky(float x) { return x >= 0.f ? x : SLOPE * x; }

__device__ __forceinline__ float bf2f(unsigned short u) {
    return __uint_as_float(((unsigned)u) << 16);
}
__device__ __forceinline__ unsigned short f2bf(float f) {
    unsigned u = __float_as_uint(f);
    unsigned r = (u + 0x7fffu + ((u >> 16) & 1u)) >> 16;
    return (unsigned short)r;
}

// 16-lane-group sum via DPP row rotations (pure VALU, no LDS pipe).
// Builtin form: the compiler interleaves these chains across unrolled edges,
// which beats a hand-fused asm block (r5 regression: asm wall -> stalls).
template <int CTRL>
__device__ __forceinline__ float ror_add(float v) {
    const int r = __builtin_amdgcn_update_dpp(0, __float_as_int(v), CTRL, 0xF, 0xF, true);
    return v + __int_as_float(r);
}
__device__ __forceinline__ float group16_sum(float v) {
    v = ror_add<0x121>(v);
    v = ror_add<0x122>(v);
    v = ror_add<0x124>(v);
    v = ror_add<0x128>(v);
    return v;
}

// ---------------------------------------------------------------------------
// prep: feat fp32->bf16 cast, 3 weight transpose+casts, zero cnt/cursor/sums/
// done (hist lives in proj; no memset).
// ---------------------------------------------------------------------------
__global__ __launch_bounds__(256) void prep_kernel(const float* __restrict__ feat,
                                                   const float* __restrict__ W_src,
                                                   const float* __restrict__ W_dst,
                                                   const float* __restrict__ fc_W,
                                                   unsigned short* __restrict__ feat_bf,
                                                   unsigned short* __restrict__ WtS,
                                                   unsigned short* __restrict__ WtD,
                                                   unsigned short* __restrict__ WtF,
                                                   int* __restrict__ cnt2,
                                                   float* __restrict__ sums,
                                                   int* __restrict__ done) {
    const int b = blockIdx.x;
    const int t = threadIdx.x;
    if (b < 12500) {
        const int i = b * 256 + t;
        const float4 v = ((const float4*)feat)[i];
        ushort4 o;
        o.x = f2bf(v.x); o.y = f2bf(v.y); o.z = f2bf(v.z); o.w = f2bf(v.w);
        ((ushort4*)feat_bf)[i] = o;
    } else if (b < 12756) {
        const int n = b - 12500;
        WtS[(size_t)n * 256 + t] = f2bf(W_src[(size_t)t * 256 + n]);
    } else if (b < 13012) {
        const int n = b - 12756;
        WtD[(size_t)n * 256 + t] = f2bf(W_dst[(size_t)t * 256 + n]);
    } else if (b < 13076) {
        const int n = b - 13012;
        WtF[(size_t)n * 256 + t] = f2bf(fc_W[(size_t)t * 64 + n]);
    } else if (b < 13174) {
        const int i = (b - 13076) * 256 + t;
        if (i < 25000) ((int4*)cnt2)[i] = make_int4(0, 0, 0, 0);
    } else {
        if (t < 128) sums[t] = 0.f;
        if (t == 128) done[0] = 0;
    }
}

// ---------------------------------------------------------------------------
// bf16 MFMA GEMM with A-register reuse across 4 column-chunk phases,
// + fused edge histogram.
// Blocks [0,96): histogram (overlaps GEMM). jid = id-96:
//   tile = (jid>>4)*8 + (jid&7), matrix = (jid>>3)&1 (S/D);
//   a tile's S/D pair sits 8 ids apart -> same XCD (%8 round-robin) ->
//   A tile read once from L3, L2-hit for the partner.
// Per block: load A fragments ONCE (16 gathers), then 4 phases of
//   {stage 64-col B chunk (XOR-swizzled) -> 32 MFMA -> wide-store epilogue}.
// vs r6 (one phase per block): 4x fewer A-gather latency events and block
//   ramps per tile — the r3 counters (MfmaUtil 7.8%, VALUBusy 9.8%) showed
//   this front-end latency dominating, not traffic (FETCH already 15.7MB).
// ---------------------------------------------------------------------------
__global__ __launch_bounds__(256) void proj_kernel(const unsigned short* __restrict__ A,
                                                   const unsigned short* __restrict__ BtS,
                                                   const unsigned short* __restrict__ BtD,
                                                   const float* __restrict__ bS,
                                                   const float* __restrict__ bD,
                                                   unsigned short* __restrict__ CS,
                                                   unsigned short* __restrict__ CD,
                                                   const int* __restrict__ dst,
                                                   int* __restrict__ cnt) {
    __shared__ unsigned short Bs[64 * 256];   // 32 KB

    if (blockIdx.x < HIST_BLOCKS) {
        for (int i = blockIdx.x * 256 + threadIdx.x; i < N_EDGES; i += HIST_BLOCKS * 256)
            atomicAdd(&cnt[dst[i]], 1);
        return;
    }

    const int jid  = blockIdx.x - HIST_BLOCKS;
    const int tile = (jid >> 4) * 8 + (jid & 7);
    if (tile >= NTILES) return;
    const bool isD = ((jid >> 3) & 1) != 0;

    const int t    = threadIdx.x;
    const int w    = t >> 6;
    const int lane = t & 63;
    const int q    = lane >> 4;
    const int l16  = lane & 15;

    const unsigned short* Bt   = isD ? BtD : BtS;
    const float*          bias = isD ? bD  : bS;
    unsigned short*       C    = isD ? CD  : CS;

    const int m0 = tile * 128;

    // ---- load A fragments ONCE (held in VGPRs across all 4 phases) ----
    int ar0 = m0 + w * 32 + l16;
    int ar1 = ar0 + 16;
    if (ar0 > N_NODES - 1) ar0 = N_NODES - 1;
    if (ar1 > N_NODES - 1) ar1 = N_NODES - 1;
    const unsigned short* Ab0 = A + (size_t)ar0 * 256 + q * 8;
    const unsigned short* Ab1 = A + (size_t)ar1 * 256 + q * 8;
    short8 afr0[8], afr1[8];
#pragma unroll
    for (int kk = 0; kk < 8; ++kk) {
        afr0[kk] = *(const short8*)(Ab0 + kk * 32);
        afr1[kk] = *(const short8*)(Ab1 + kk * 32);
    }

    // staging thread mapping (constant across phases)
    const int r   = t >> 2;        // B row (= output col within chunk) 0..63
    const int seg = t & 3;
    const int cc  = r >> 4;
    const int L   = r & 15;

    const int la8 = lane * 8;
    const int lsw[4] = {la8, la8 ^ 16, la8 ^ 32, la8 ^ 48};

    for (int ph = 0; ph < 4; ++ph) {
        const int c0 = ph * 64;

        __syncthreads();   // prior phase's epilogue LDS reads complete
        // ---- stage B chunk, fragment order, XOR-swizzled ----
        {
            const unsigned short* g = Bt + (size_t)(c0 + r) * 256 + seg * 64;
#pragma unroll
            for (int kk2 = 0; kk2 < 2; ++kk2) {
                const int kk   = seg * 2 + kk2;
                const int c8kk = cc * 8 + kk;
                const int key  = ((c8kk >> 1) & 3) << 4;
#pragma unroll
                for (int q2 = 0; q2 < 4; ++q2)
                    *(short8*)(&Bs[((c8kk * 64 + q2 * 16 + L) * 8) ^ key]) =
                        *(const short8*)(g + kk2 * 32 + q2 * 8);
            }
        }
        __syncthreads();

        float vb[4];
#pragma unroll
        for (int c = 0; c < 4; ++c) vb[c] = bias[c0 + c * 16 + l16];

        float4v a0[4] = {}, a1[4] = {};
#pragma unroll
        for (int kk = 0; kk < 8; ++kk) {
            const short8 af0 = afr0[kk];
            const short8 af1 = afr1[kk];
#pragma unroll
            for (int c = 0; c < 4; ++c) {
                const int c8kk = c * 8 + kk;
                const short8 b = *(const short8*)(&Bs[c8kk * 512 + lsw[(c8kk >> 1) & 3]]);
                a0[c] = __builtin_amdgcn_mfma_f32_16x16x32_bf16(af0, b, a0[c], 0, 0, 0);
                a1[c] = __builtin_amdgcn_mfma_f32_16x16x32_bf16(af1, b, a1[c], 0, 0, 0);
            }
        }

        __syncthreads();   // all waves' MFMA B-reads done before Bs reuse
        // ---- transposing epilogue through LDS (per-wave region) ----
        unsigned short* Cw = Bs + w * 2304;    // 32 rows x 64 cols, stride 72
#pragma unroll
        for (int c = 0; c < 4; ++c) {
            const int cl = c * 16 + l16;
#pragma unroll
            for (int i = 0; i < 4; ++i) {
                Cw[(q * 4 + i) * 72 + cl]      = f2bf(a0[c][i] + vb[c]);
                Cw[(q * 4 + i + 16) * 72 + cl] = f2bf(a1[c][i] + vb[c]);
            }
        }
        // per-wave area: wave-local lgkmcnt ordering, no barrier needed here
#pragma unroll
        for (int j = 0; j < 4; ++j) {
            const int rl = j * 8 + (lane >> 3);    // local row 0..31
            const short8 v = *(const short8*)(Cw + rl * 72 + (lane & 7) * 8);
            const int rg = m0 + w * 32 + rl;
            if (rg < N_NODES)
                *(short8*)(&C[(size_t)rg * 256 + c0 + (lane & 7) * 8]) = v;
        }
    }
}

// ---------------------------------------------------------------------------
// fc GEMM (bf16 MFMA, fp32 out) + fused BatchNorm partial-stats epilogue.
// ---------------------------------------------------------------------------
__global__ __launch_bounds__(256) void fc_bn_kernel(const unsigned short* __restrict__ A,
                                                    const unsigned short* __restrict__ Bt,
                                                    const float* __restrict__ bias,
                                                    float* __restrict__ C,
                                                    float* __restrict__ sums,
                                                    int M) {
    const int w    = threadIdx.x >> 6;
    const int lane = threadIdx.x & 63;
    const int q    = lane >> 4;
    const int l16  = lane & 15;
    const int m0   = blockIdx.x * 64;
    const int t    = threadIdx.x;

    __shared__ float ssum[64], ssq[64];
    if (t < 64) { ssum[t] = 0.f; ssq[t] = 0.f; }

    int arow = m0 + w * 16 + l16;
    if (arow > M - 1) arow = M - 1;
    const unsigned short* Ab  = A  + (size_t)arow * 256 + q * 8;
    const unsigned short* Btb = Bt + (size_t)l16 * 256 + q * 8;

    float4v acc[4] = {};

    for (int k0 = 0; k0 < 256; k0 += 32) {
        const short8 af = *(const short8*)(Ab + k0);
#pragma unroll
        for (int c = 0; c < 4; ++c) {
            const short8 bf = *(const short8*)(Btb + (size_t)c * 16 * 256 + k0);
            acc[c] = __builtin_amdgcn_mfma_f32_16x16x32_bf16(af, bf, acc[c], 0, 0, 0);
        }
    }
    __syncthreads();

#pragma unroll
    for (int c = 0; c < 4; ++c) {
        const int col = c * 16 + l16;
        const float b = bias[col];
        float s = 0.f, qq = 0.f;
#pragma unroll
        for (int i = 0; i < 4; ++i) {
            const int r = m0 + w * 16 + q * 4 + i;
            if (r < M) {
                const float v = acc[c][i] + b;
                C[(size_t)r * 64 + col] = v;
                s += v;
                qq += v * v;
            }
        }
        atomicAdd(&ssum[col], s);
        atomicAdd(&ssq[col], qq);
    }
    __syncthreads();
    if (t < 64) {
        atomicAdd(&sums[t], ssum[t]);
        atomicAdd(&sums[64 + t], ssq[t]);
    }
}

// ---------------------------------------------------------------------------
// CSR build: merged 2-level scan (last-block does chunk-sum scan); scatter.
// ---------------------------------------------------------------------------
__global__ __launch_bounds__(512) void scan_kernel(const int* __restrict__ cnt,
                                                   int* __restrict__ offs,
                                                   int* __restrict__ bsum,
                                                   int* __restrict__ bpre,
                                                   int* __restrict__ done) {
    __shared__ int s[512];
    __shared__ bool amLast;
    const int t = threadIdx.x;
    const int i = blockIdx.x * 512 + t;
    const int v = (i < N_NODES) ? cnt[i] : 0;
    s[t] = v;
    __syncthreads();
    for (int off = 1; off < 512; off <<= 1) {
        const int x = (t >= off) ? s[t - off] : 0;
        __syncthreads();
        s[t] += x;
        __syncthreads();
    }
    if (i < N_NODES) offs[i] = s[t] - v;       // exclusive within chunk
    if (t == 511) {
        bsum[blockIdx.x] = s[511];
        __threadfence();
        amLast = (atomicAdd(done, 1) == (int)gridDim.x - 1);
    }
    __syncthreads();
    if (amLast) {
        const int v2 = (t < (int)gridDim.x) ? atomicAdd(&bsum[t], 0) : 0;
        s[t] = v2;
        __syncthreads();
        for (int off = 1; off < 512; off <<= 1) {
            const int x = (t >= off) ? s[t - off] : 0;
            __syncthreads();
            s[t] += x;
            __syncthreads();
        }
        if (t < (int)gridDim.x) bpre[t] = s[t] - v2;
    }
}

__global__ void scatter_kernel(const int* __restrict__ src,
                               const int* __restrict__ dst,
                               const int* __restrict__ offs,
                               const int* __restrict__ bpre,
                               int* __restrict__ cursor,
                               int* __restrict__ srcl) {
    const int i = blockIdx.x * 256 + threadIdx.x;
    if (i < N_EDGES) {
        const int d = dst[i];
        const int p = offs[d] + bpre[d >> 9] + atomicAdd(&cursor[d], 1);
        srcl[p] = src[i];
    }
}

// ---------------------------------------------------------------------------
// Fused GATv2 score + softmax + aggregation: one wave per node, 4 nodes per
// 256-thread block (verified configuration: 64.0-64.6 us). Unroll x4;
// src ids moved to SGPRs via readfirstlane so gathers are saddr-form.
// leaky-dot via 2 FMAs/dim: attn.leaky(y) = c1*y + c2*|y|  (|y| is a free
// VOP3 src modifier). DPP group reductions (builtin; compiler-scheduled).
// No-max exponentials (|e| << 88; exactly softmax).
// ---------------------------------------------------------------------------
__global__ __launch_bounds__(256) void agg_fused_kernel(const unsigned short* __restrict__ h_src,
                                                        const unsigned short* __restrict__ h_dst,
                                                        const int* __restrict__ srcl,
                                                        const int* __restrict__ offs,
                                                        const int* __restrict__ bpre,
                                                        const float* __restrict__ attn,
                                                        const float* __restrict__ out_bias,
                                                        unsigned short* __restrict__ rst) {
    const int node = blockIdx.x * 4 + (threadIdx.x >> 6);
    const int lane = threadIdx.x & 63;
    const int d4 = lane * 4;

    const int beg = offs[node] + bpre[node >> 9];
    const int end = (node + 1 == N_NODES) ? N_EDGES
                                          : (offs[node + 1] + bpre[(node + 1) >> 9]);

    const uint2 hdu = *(const uint2*)(h_dst + (size_t)node * 256 + d4);
    const float hd0 = __uint_as_float(hdu.x << 16);
    const float hd1 = __uint_as_float(hdu.x & 0xffff0000u);
    const float hd2 = __uint_as_float(hdu.y << 16);
    const float hd3 = __uint_as_float(hdu.y & 0xffff0000u);

    const float4 araw = *(const float4*)(attn + d4);
    const float c10 = araw.x * (0.6f * LOG2E), c20 = araw.x * (0.4f * LOG2E);
    const float c11 = araw.y * (0.6f * LOG2E), c21 = araw.y * (0.4f * LOG2E);
    const float c12 = araw.z * (0.6f * LOG2E), c22 = araw.z * (0.4f * LOG2E);
    const float c13 = araw.w * (0.6f * LOG2E), c23 = araw.w * (0.4f * LOG2E);

    float wsum = 0.f, a0 = 0.f, a1 = 0.f, a2 = 0.f, a3 = 0.f;

    // one edge: returns weight, accumulates
#define EDGE_BODY(sreg)                                                          \
    {                                                                            \
        const unsigned short* row = h_src + (size_t)(sreg) * 256;                \
        const uint2 u = *(const uint2*)(row + d4);                               \
        const float r0 = __uint_as_float(u.x << 16);                             \
        const float r1 = __uint_as_float(u.x & 0xffff0000u);                     \
        const float r2 = __uint_as_float(u.y << 16);                             \
        const float r3 = __uint_as_float(u.y & 0xffff0000u);                     \
        const float y0 = r0 + hd0, y1 = r1 + hd1, y2 = r2 + hd2, y3 = r3 + hd3;  \
        float pp = fmaf(c10, y0, c20 * __builtin_fabsf(y0));                     \
        pp = fmaf(c11, y1, fmaf(c21, __builtin_fabsf(y1), pp));                  \
        pp = fmaf(c12, y2, fmaf(c22, __builtin_fabsf(y2), pp));                  \
        pp = fmaf(c13, y3, fmaf(c23, __builtin_fabsf(y3), pp));                  \
        pp = group16_sum(pp);                                                    \
        const float wg = __builtin_amdgcn_exp2f(pp);                             \
        wsum += wg;                                                              \
        a0 = fmaf(wg, r0, a0);                                                   \
        a1 = fmaf(wg, r1, a1);                                                   \
        a2 = fmaf(wg, r2, a2);                                                   \
        a3 = fmaf(wg, r3, a3);                                                   \
    }

    int p = beg;
    const int nfull = (end - beg) >> 2;
    for (int it = 0; it < nfull; ++it, p += 4) {
        const int s0 = __builtin_amdgcn_readfirstlane(srcl[p]);
        const int s1 = __builtin_amdgcn_readfirstlane(srcl[p + 1]);
        const int s2 = __builtin_amdgcn_readfirstlane(srcl[p + 2]);
        const int s3 = __builtin_amdgcn_readfirstlane(srcl[p + 3]);
        EDGE_BODY(s0);
        EDGE_BODY(s1);
        EDGE_BODY(s2);
        EDGE_BODY(s3);
    }
    for (; p < end; ++p) {
        const int s0 = __builtin_amdgcn_readfirstlane(srcl[p]);
        EDGE_BODY(s0);
    }
#undef EDGE_BODY

    const float inv = (wsum > 0.f) ? 1.f / wsum : 0.f;
    const float4 ob = *(const float4*)(out_bias + d4);
    ushort4 o;
    o.x = f2bf(fmaf(a0, inv, ob.x));
    o.y = f2bf(fmaf(a1, inv, ob.y));
    o.z = f2bf(fmaf(a2, inv, ob.z));
    o.w = f2bf(fmaf(a3, inv, ob.w));
    *(ushort4*)(rst + (size_t)node * 256 + d4) = o;
}

// ---------------------------------------------------------------------------
// BatchNorm finalize + LeakyReLU (float4-vectorized streaming pass)
// ---------------------------------------------------------------------------
__global__ __launch_bounds__(256) void bn_final_kernel(float* __restrict__ z,
                                                       const float* __restrict__ sums,
                                                       const float* __restrict__ gamma,
                                                       const float* __restrict__ beta) {
    const int i = blockIdx.x * 256 + threadIdx.x;    // index of a float4 group
    if (i < N_NODES * 16) {
        const int c4 = (i & 15) * 4;                 // column of first component
        float4 v = ((const float4*)z)[i];
        float out[4] = {v.x, v.y, v.z, v.w};
#pragma unroll
        for (int j = 0; j < 4; ++j) {
            const int col = c4 + j;
            const float mu  = sums[col] * (1.f / N_NODES);
            const float var = sums[64 + col] * (1.f / N_NODES) - mu * mu;
            const float sc  = rsqrtf(var + BN_EPS) * gamma[col];
            const float sh  = beta[col] - mu * sc;
            out[j] = leaky(fmaf(out[j], sc, sh));
        }
        ((float4*)z)[i] = make_float4(out[0], out[1], out[2], out[3]);
    }
}

// ---------------------------------------------------------------------------
extern "C" void kernel_launch(void* const* d_in, const int* in_sizes, int n_in,
                              void* d_out, int out_size, void* d_ws, size_t ws_size,
                              hipStream_t stream) {
    const float* feat    = (const float*)d_in[0];
    const int*   src     = (const int*)  d_in[1];
    const int*   dst     = (const int*)  d_in[2];
    const float* W_src   = (const float*)d_in[3];
    const float* b_src   = (const float*)d_in[4];
    const float* W_dst   = (const float*)d_in[5];
    const float* b_dst   = (const float*)d_in[6];
    const float* attn    = (const float*)d_in[7];
    const float* out_bias= (const float*)d_in[8];
    const float* fc_W    = (const float*)d_in[9];
    const float* fc_b    = (const float*)d_in[10];
    const float* gamma   = (const float*)d_in[11];
    const float* beta    = (const float*)d_in[12];
    float* z = (float*)d_out;

    char* ws = (char*)d_ws;
    size_t off = 0;
    auto carve = [&](size_t bytes) -> void* {
        void* p = ws + off;
        off = (off + bytes + 255) & ~(size_t)255;
        return p;
    };
    unsigned short* feat_bf = (unsigned short*)carve((size_t)N_NODES * 256 * 2);
    unsigned short* h_src_bf= (unsigned short*)carve((size_t)N_NODES * 256 * 2);
    unsigned short* h_dst_bf= (unsigned short*)carve((size_t)N_NODES * 256 * 2);
    unsigned short* rst_bf  = (unsigned short*)carve((size_t)N_NODES * 256 * 2);
    unsigned short* WtS     = (unsigned short*)carve((size_t)256 * 256 * 2);
    unsigned short* WtD     = (unsigned short*)carve((size_t)256 * 256 * 2);
    unsigned short* WtF     = (unsigned short*)carve((size_t)64 * 256 * 2);
    int*   srcl   = (int*)  carve((size_t)N_EDGES * 4);
    int*   cnt    = (int*)  carve((size_t)2 * N_NODES * 4);
    int*   cursor = cnt + N_NODES;
    int*   offs   = (int*)  carve((size_t)(N_NODES + 1) * 4);
    int*   bsum   = (int*)  carve(128 * 4);
    int*   bpre   = (int*)  carve(128 * 4);
    float* sums   = (float*)carve(128 * 4);
    int*   done   = (int*)  carve(64);

    const int nchunks = (N_NODES + 511) / 512;      // 98

    // prep: cast + transposes + zeroing
    prep_kernel<<<13175, 256, 0, stream>>>(feat, W_src, W_dst, fc_W,
                                           feat_bf, WtS, WtD, WtF, cnt, sums, done);

    // input projections (A-resident 4-phase blocks, XCD-paired S/D jobs,
    // swizzled LDS, wide-store epilogue) + fused histogram
    proj_kernel<<<HIST_BLOCKS + NGROUPS * 16, 256, 0, stream>>>(
        feat_bf, WtS, WtD, b_src, b_dst, h_src_bf, h_dst_bf, dst, cnt);

    // CSR by dst (merged scan -> scatter)
    scan_kernel<<<nchunks, 512, 0, stream>>>(cnt, offs, bsum, bpre, done);
    scatter_kernel<<<(N_EDGES + 255) / 256, 256, 0, stream>>>(src, dst, offs, bpre, cursor, srcl);

    // fused score + softmax + aggregation (1 wave per node, DPP reductions)
    agg_fused_kernel<<<N_NODES / 4, 256, 0, stream>>>(h_src_bf, h_dst_bf, srcl, offs, bpre,
                                                      attn, out_bias, rst_bf);

    // trailing fc + BN partial stats
    fc_bn_kernel<<<(N_NODES + 63) / 64, 256, 0, stream>>>(rst_bf, WtF, fc_b, z, sums, N_NODES);

    // batchnorm finalize + leaky (vectorized)
    bn_final_kernel<<<(N_NODES * 16 + 255) / 256, 256, 0, stream>>>(z, sums, gamma, beta);
}

// Round 8
// 311.620 us; speedup vs baseline: 1.0879x; 1.0006x over previous
//
#include <hip/hip_runtime.h>
#include <math.h>

#define N_NODES 50000
#define N_EDGES 800000
#define HD 256          // NHEAD * OUT_DIM
#define OUT_DIM 64
#define NHEAD 4
#define SLOPE 0.2f
#define BN_EPS 1e-5f
#define LOG2E 1.4426950408889634f
#define NTILES 391      // ceil(N_NODES / 128)
#define HIST_BLOCKS 96

typedef __attribute__((ext_vector_type(8))) short short8;
typedef __attribute__((ext_vector_type(4))) float float4v;

__device__ __forceinline__ float leaky(float x) { return x >= 0.f ? x : SLOPE * x; }

__device__ __forceinline__ float bf2f(unsigned short u) {
    return __uint_as_float(((unsigned)u) << 16);
}
__device__ __forceinline__ unsigned short f2bf(float f) {
    unsigned u = __float_as_uint(f);
    unsigned r = (u + 0x7fffu + ((u >> 16) & 1u)) >> 16;
    return (unsigned short)r;
}

// pack 8 fp32 -> 8 bf16 (RNE, matches prep's cast exactly)
__device__ __forceinline__ short8 pack8(const float4 a, const float4 b) {
    short8 r;
    r[0] = (short)f2bf(a.x); r[1] = (short)f2bf(a.y);
    r[2] = (short)f2bf(a.z); r[3] = (short)f2bf(a.w);
    r[4] = (short)f2bf(b.x); r[5] = (short)f2bf(b.y);
    r[6] = (short)f2bf(b.z); r[7] = (short)f2bf(b.w);
    return r;
}

// 16-lane-group sum via DPP row rotations (pure VALU, no LDS pipe).
// Builtin form: the compiler interleaves these chains across unrolled edges,
// which beats a hand-fused asm block (r5 regression: asm wall -> stalls).
template <int CTRL>
__device__ __forceinline__ float ror_add(float v) {
    const int r = __builtin_amdgcn_update_dpp(0, __float_as_int(v), CTRL, 0xF, 0xF, true);
    return v + __int_as_float(r);
}
__device__ __forceinline__ float group16_sum(float v) {
    v = ror_add<0x121>(v);
    v = ror_add<0x122>(v);
    v = ror_add<0x124>(v);
    v = ror_add<0x128>(v);
    return v;
}

// ---------------------------------------------------------------------------
// prep: 3 weight transpose+casts, zero cnt/cursor/sums/done.
// (feat cast is fused into proj's A load now — no 76.8MB streaming pass.)
// ---------------------------------------------------------------------------
__global__ __launch_bounds__(256) void prep_kernel(const float* __restrict__ W_src,
                                                   const float* __restrict__ W_dst,
                                                   const float* __restrict__ fc_W,
                                                   unsigned short* __restrict__ WtS,
                                                   unsigned short* __restrict__ WtD,
                                                   unsigned short* __restrict__ WtF,
                                                   int* __restrict__ cnt2,
                                                   float* __restrict__ sums,
                                                   int* __restrict__ done) {
    const int b = blockIdx.x;
    const int t = threadIdx.x;
    if (b < 256) {
        WtS[(size_t)b * 256 + t] = f2bf(W_src[(size_t)t * 256 + b]);
    } else if (b < 512) {
        const int n = b - 256;
        WtD[(size_t)n * 256 + t] = f2bf(W_dst[(size_t)t * 256 + n]);
    } else if (b < 576) {
        const int n = b - 512;
        WtF[(size_t)n * 256 + t] = f2bf(fc_W[(size_t)t * 64 + n]);
    } else if (b < 674) {
        const int i = (b - 576) * 256 + t;
        if (i < 25000) ((int4*)cnt2)[i] = make_int4(0, 0, 0, 0);
    } else {
        if (t < 128) sums[t] = 0.f;
        if (t == 128) done[0] = 0;
    }
}

// ---------------------------------------------------------------------------
// bf16 MFMA GEMM: ONE block per 128-row tile, A loaded fp32 ONCE (fused
// cast), then 8 phases = {S,D} x 4 column chunks, + fused edge histogram.
// Blocks [0,96): histogram (overlaps GEMM). jid = id-96 = tile.
// Per block: 32 fp32 gathers + 128 f2bf (one-time), then per phase
//   {stage 64-col B chunk (XOR-swizzled) -> 32 MFMA -> wide-store epilogue}.
// vs r7: A-gather latency events per tile halved again (2 blocks -> 1),
//   prep's 76.8MB cast pass deleted (feat read fp32 exactly once), and the
//   487-block grid is single-round co-resident (no turnover tail).
// ---------------------------------------------------------------------------
__global__ __launch_bounds__(256) void proj_kernel(const float* __restrict__ feat,
                                                   const unsigned short* __restrict__ BtS,
                                                   const unsigned short* __restrict__ BtD,
                                                   const float* __restrict__ bS,
                                                   const float* __restrict__ bD,
                                                   unsigned short* __restrict__ CS,
                                                   unsigned short* __restrict__ CD,
                                                   const int* __restrict__ dst,
                                                   int* __restrict__ cnt) {
    __shared__ unsigned short Bs[64 * 256];   // 32 KB

    if (blockIdx.x < HIST_BLOCKS) {
        for (int i = blockIdx.x * 256 + threadIdx.x; i < N_EDGES; i += HIST_BLOCKS * 256)
            atomicAdd(&cnt[dst[i]], 1);
        return;
    }

    const int tile = blockIdx.x - HIST_BLOCKS;
    if (tile >= NTILES) return;

    const int t    = threadIdx.x;
    const int w    = t >> 6;
    const int lane = t & 63;
    const int q    = lane >> 4;
    const int l16  = lane & 15;

    const int m0 = tile * 128;

    // ---- load A fragments ONCE as fp32, cast in registers (fused cast) ----
    int ar0 = m0 + w * 32 + l16;
    int ar1 = ar0 + 16;
    if (ar0 > N_NODES - 1) ar0 = N_NODES - 1;
    if (ar1 > N_NODES - 1) ar1 = N_NODES - 1;
    const float* Af0 = feat + (size_t)ar0 * 256 + q * 8;
    const float* Af1 = feat + (size_t)ar1 * 256 + q * 8;
    short8 afr0[8], afr1[8];
#pragma unroll
    for (int kk = 0; kk < 8; ++kk) {
        const float4 x0 = *(const float4*)(Af0 + kk * 32);
        const float4 y0 = *(const float4*)(Af0 + kk * 32 + 4);
        const float4 x1 = *(const float4*)(Af1 + kk * 32);
        const float4 y1 = *(const float4*)(Af1 + kk * 32 + 4);
        afr0[kk] = pack8(x0, y0);
        afr1[kk] = pack8(x1, y1);
    }

    // staging thread mapping (constant across phases)
    const int r   = t >> 2;        // B row (= output col within chunk) 0..63
    const int seg = t & 3;
    const int cc  = r >> 4;
    const int L   = r & 15;

    const int la8 = lane * 8;
    const int lsw[4] = {la8, la8 ^ 16, la8 ^ 32, la8 ^ 48};

    for (int ph = 0; ph < 8; ++ph) {
        const bool isD = (ph >= 4);
        const int  c0  = (ph & 3) * 64;
        const unsigned short* Bt   = isD ? BtD : BtS;
        const float*          bias = isD ? bD  : bS;
        unsigned short*       C    = isD ? CD  : CS;

        __syncthreads();   // prior phase's epilogue LDS reads complete
        // ---- stage B chunk, fragment order, XOR-swizzled ----
        {
            const unsigned short* g = Bt + (size_t)(c0 + r) * 256 + seg * 64;
#pragma unroll
            for (int kk2 = 0; kk2 < 2; ++kk2) {
                const int kk   = seg * 2 + kk2;
                const int c8kk = cc * 8 + kk;
                const int key  = ((c8kk >> 1) & 3) << 4;
#pragma unroll
                for (int q2 = 0; q2 < 4; ++q2)
                    *(short8*)(&Bs[((c8kk * 64 + q2 * 16 + L) * 8) ^ key]) =
                        *(const short8*)(g + kk2 * 32 + q2 * 8);
            }
        }
        __syncthreads();

        float vb[4];
#pragma unroll
        for (int c = 0; c < 4; ++c) vb[c] = bias[c0 + c * 16 + l16];

        float4v a0[4] = {}, a1[4] = {};
#pragma unroll
        for (int kk = 0; kk < 8; ++kk) {
            const short8 af0 = afr0[kk];
            const short8 af1 = afr1[kk];
#pragma unroll
            for (int c = 0; c < 4; ++c) {
                const int c8kk = c * 8 + kk;
                const short8 b = *(const short8*)(&Bs[c8kk * 512 + lsw[(c8kk >> 1) & 3]]);
                a0[c] = __builtin_amdgcn_mfma_f32_16x16x32_bf16(af0, b, a0[c], 0, 0, 0);
                a1[c] = __builtin_amdgcn_mfma_f32_16x16x32_bf16(af1, b, a1[c], 0, 0, 0);
            }
        }

        __syncthreads();   // all waves' MFMA B-reads done before Bs reuse
        // ---- transposing epilogue through LDS (per-wave region) ----
        unsigned short* Cw = Bs + w * 2304;    // 32 rows x 64 cols, stride 72
#pragma unroll
        for (int c = 0; c < 4; ++c) {
            const int cl = c * 16 + l16;
#pragma unroll
            for (int i = 0; i < 4; ++i) {
                Cw[(q * 4 + i) * 72 + cl]      = f2bf(a0[c][i] + vb[c]);
                Cw[(q * 4 + i + 16) * 72 + cl] = f2bf(a1[c][i] + vb[c]);
            }
        }
        // per-wave area: wave-local lgkmcnt ordering, no barrier needed here
#pragma unroll
        for (int j = 0; j < 4; ++j) {
            const int rl = j * 8 + (lane >> 3);    // local row 0..31
            const short8 v = *(const short8*)(Cw + rl * 72 + (lane & 7) * 8);
            const int rg = m0 + w * 32 + rl;
            if (rg < N_NODES)
                *(short8*)(&C[(size_t)rg * 256 + c0 + (lane & 7) * 8]) = v;
        }
    }
}

// ---------------------------------------------------------------------------
// fc GEMM (bf16 MFMA, fp32 out) + fused BatchNorm partial-stats epilogue.
// ---------------------------------------------------------------------------
__global__ __launch_bounds__(256) void fc_bn_kernel(const unsigned short* __restrict__ A,
                                                    const unsigned short* __restrict__ Bt,
                                                    const float* __restrict__ bias,
                                                    float* __restrict__ C,
                                                    float* __restrict__ sums,
                                                    int M) {
    const int w    = threadIdx.x >> 6;
    const int lane = threadIdx.x & 63;
    const int q    = lane >> 4;
    const int l16  = lane & 15;
    const int m0   = blockIdx.x * 64;
    const int t    = threadIdx.x;

    __shared__ float ssum[64], ssq[64];
    if (t < 64) { ssum[t] = 0.f; ssq[t] = 0.f; }

    int arow = m0 + w * 16 + l16;
    if (arow > M - 1) arow = M - 1;
    const unsigned short* Ab  = A  + (size_t)arow * 256 + q * 8;
    const unsigned short* Btb = Bt + (size_t)l16 * 256 + q * 8;

    float4v acc[4] = {};

    for (int k0 = 0; k0 < 256; k0 += 32) {
        const short8 af = *(const short8*)(Ab + k0);
#pragma unroll
        for (int c = 0; c < 4; ++c) {
            const short8 bf = *(const short8*)(Btb + (size_t)c * 16 * 256 + k0);
            acc[c] = __builtin_amdgcn_mfma_f32_16x16x32_bf16(af, bf, acc[c], 0, 0, 0);
        }
    }
    __syncthreads();

#pragma unroll
    for (int c = 0; c < 4; ++c) {
        const int col = c * 16 + l16;
        const float b = bias[col];
        float s = 0.f, qq = 0.f;
#pragma unroll
        for (int i = 0; i < 4; ++i) {
            const int r = m0 + w * 16 + q * 4 + i;
            if (r < M) {
                const float v = acc[c][i] + b;
                C[(size_t)r * 64 + col] = v;
                s += v;
                qq += v * v;
            }
        }
        atomicAdd(&ssum[col], s);
        atomicAdd(&ssq[col], qq);
    }
    __syncthreads();
    if (t < 64) {
        atomicAdd(&sums[t], ssum[t]);
        atomicAdd(&sums[64 + t], ssq[t]);
    }
}

// ---------------------------------------------------------------------------
// CSR build: merged 2-level scan (last-block does chunk-sum scan); scatter.
// ---------------------------------------------------------------------------
__global__ __launch_bounds__(512) void scan_kernel(const int* __restrict__ cnt,
                                                   int* __restrict__ offs,
                                                   int* __restrict__ bsum,
                                                   int* __restrict__ bpre,
                                                   int* __restrict__ done) {
    __shared__ int s[512];
    __shared__ bool amLast;
    const int t = threadIdx.x;
    const int i = blockIdx.x * 512 + t;
    const int v = (i < N_NODES) ? cnt[i] : 0;
    s[t] = v;
    __syncthreads();
    for (int off = 1; off < 512; off <<= 1) {
        const int x = (t >= off) ? s[t - off] : 0;
        __syncthreads();
        s[t] += x;
        __syncthreads();
    }
    if (i < N_NODES) offs[i] = s[t] - v;       // exclusive within chunk
    if (t == 511) {
        bsum[blockIdx.x] = s[511];
        __threadfence();
        amLast = (atomicAdd(done, 1) == (int)gridDim.x - 1);
    }
    __syncthreads();
    if (amLast) {
        const int v2 = (t < (int)gridDim.x) ? atomicAdd(&bsum[t], 0) : 0;
        s[t] = v2;
        __syncthreads();
        for (int off = 1; off < 512; off <<= 1) {
            const int x = (t >= off) ? s[t - off] : 0;
            __syncthreads();
            s[t] += x;
            __syncthreads();
        }
        if (t < (int)gridDim.x) bpre[t] = s[t] - v2;
    }
}

__global__ void scatter_kernel(const int* __restrict__ src,
                               const int* __restrict__ dst,
                               const int* __restrict__ offs,
                               const int* __restrict__ bpre,
                               int* __restrict__ cursor,
                               int* __restrict__ srcl) {
    const int i = blockIdx.x * 256 + threadIdx.x;
    if (i < N_EDGES) {
        const int d = dst[i];
        const int p = offs[d] + bpre[d >> 9] + atomicAdd(&cursor[d], 1);
        srcl[p] = src[i];
    }
}

// ---------------------------------------------------------------------------
// Fused GATv2 score + softmax + aggregation: one wave per node, 4 nodes per
// 256-thread block (verified configuration: 64.0-64.6 us). Unroll x4;
// src ids moved to SGPRs via readfirstlane so gathers are saddr-form.
// leaky-dot via 2 FMAs/dim: attn.leaky(y) = c1*y + c2*|y|  (|y| is a free
// VOP3 src modifier). DPP group reductions (builtin; compiler-scheduled).
// No-max exponentials (|e| << 88; exactly softmax).
// ---------------------------------------------------------------------------
__global__ __launch_bounds__(256) void agg_fused_kernel(const unsigned short* __restrict__ h_src,
                                                        const unsigned short* __restrict__ h_dst,
                                                        const int* __restrict__ srcl,
                                                        const int* __restrict__ offs,
                                                        const int* __restrict__ bpre,
                                                        const float* __restrict__ attn,
                                                        const float* __restrict__ out_bias,
                                                        unsigned short* __restrict__ rst) {
    const int node = blockIdx.x * 4 + (threadIdx.x >> 6);
    const int lane = threadIdx.x & 63;
    const int d4 = lane * 4;

    const int beg = offs[node] + bpre[node >> 9];
    const int end = (node + 1 == N_NODES) ? N_EDGES
                                          : (offs[node + 1] + bpre[(node + 1) >> 9]);

    const uint2 hdu = *(const uint2*)(h_dst + (size_t)node * 256 + d4);
    const float hd0 = __uint_as_float(hdu.x << 16);
    const float hd1 = __uint_as_float(hdu.x & 0xffff0000u);
    const float hd2 = __uint_as_float(hdu.y << 16);
    const float hd3 = __uint_as_float(hdu.y & 0xffff0000u);

    const float4 araw = *(const float4*)(attn + d4);
    const float c10 = araw.x * (0.6f * LOG2E), c20 = araw.x * (0.4f * LOG2E);
    const float c11 = araw.y * (0.6f * LOG2E), c21 = araw.y * (0.4f * LOG2E);
    const float c12 = araw.z * (0.6f * LOG2E), c22 = araw.z * (0.4f * LOG2E);
    const float c13 = araw.w * (0.6f * LOG2E), c23 = araw.w * (0.4f * LOG2E);

    float wsum = 0.f, a0 = 0.f, a1 = 0.f, a2 = 0.f, a3 = 0.f;

    // one edge: returns weight, accumulates
#define EDGE_BODY(sreg)                                                          \
    {                                                                            \
        const unsigned short* row = h_src + (size_t)(sreg) * 256;                \
        const uint2 u = *(const uint2*)(row + d4);                               \
        const float r0 = __uint_as_float(u.x << 16);                             \
        const float r1 = __uint_as_float(u.x & 0xffff0000u);                     \
        const float r2 = __uint_as_float(u.y << 16);                             \
        const float r3 = __uint_as_float(u.y & 0xffff0000u);                     \
        const float y0 = r0 + hd0, y1 = r1 + hd1, y2 = r2 + hd2, y3 = r3 + hd3;  \
        float pp = fmaf(c10, y0, c20 * __builtin_fabsf(y0));                     \
        pp = fmaf(c11, y1, fmaf(c21, __builtin_fabsf(y1), pp));                  \
        pp = fmaf(c12, y2, fmaf(c22, __builtin_fabsf(y2), pp));                  \
        pp = fmaf(c13, y3, fmaf(c23, __builtin_fabsf(y3), pp));                  \
        pp = group16_sum(pp);                                                    \
        const float wg = __builtin_amdgcn_exp2f(pp);                             \
        wsum += wg;                                                              \
        a0 = fmaf(wg, r0, a0);                                                   \
        a1 = fmaf(wg, r1, a1);                                                   \
        a2 = fmaf(wg, r2, a2);                                                   \
        a3 = fmaf(wg, r3, a3);                                                   \
    }

    int p = beg;
    const int nfull = (end - beg) >> 2;
    for (int it = 0; it < nfull; ++it, p += 4) {
        const int s0 = __builtin_amdgcn_readfirstlane(srcl[p]);
        const int s1 = __builtin_amdgcn_readfirstlane(srcl[p + 1]);
        const int s2 = __builtin_amdgcn_readfirstlane(srcl[p + 2]);
        const int s3 = __builtin_amdgcn_readfirstlane(srcl[p + 3]);
        EDGE_BODY(s0);
        EDGE_BODY(s1);
        EDGE_BODY(s2);
        EDGE_BODY(s3);
    }
    for (; p < end; ++p) {
        const int s0 = __builtin_amdgcn_readfirstlane(srcl[p]);
        EDGE_BODY(s0);
    }
#undef EDGE_BODY

    const float inv = (wsum > 0.f) ? 1.f / wsum : 0.f;
    const float4 ob = *(const float4*)(out_bias + d4);
    ushort4 o;
    o.x = f2bf(fmaf(a0, inv, ob.x));
    o.y = f2bf(fmaf(a1, inv, ob.y));
    o.z = f2bf(fmaf(a2, inv, ob.z));
    o.w = f2bf(fmaf(a3, inv, ob.w));
    *(ushort4*)(rst + (size_t)node * 256 + d4) = o;
}

// ---------------------------------------------------------------------------
// BatchNorm finalize + LeakyReLU (float4-vectorized streaming pass)
// ---------------------------------------------------------------------------
__global__ __launch_bounds__(256) void bn_final_kernel(float* __restrict__ z,
                                                       const float* __restrict__ sums,
                                                       const float* __restrict__ gamma,
                                                       const float* __restrict__ beta) {
    const int i = blockIdx.x * 256 + threadIdx.x;    // index of a float4 group
    if (i < N_NODES * 16) {
        const int c4 = (i & 15) * 4;                 // column of first component
        float4 v = ((const float4*)z)[i];
        float out[4] = {v.x, v.y, v.z, v.w};
#pragma unroll
        for (int j = 0; j < 4; ++j) {
            const int col = c4 + j;
            const float mu  = sums[col] * (1.f / N_NODES);
            const float var = sums[64 + col] * (1.f / N_NODES) - mu * mu;
            const float sc  = rsqrtf(var + BN_EPS) * gamma[col];
            const float sh  = beta[col] - mu * sc;
            out[j] = leaky(fmaf(out[j], sc, sh));
        }
        ((float4*)z)[i] = make_float4(out[0], out[1], out[2], out[3]);
    }
}

// ---------------------------------------------------------------------------
extern "C" void kernel_launch(void* const* d_in, const int* in_sizes, int n_in,
                              void* d_out, int out_size, void* d_ws, size_t ws_size,
                              hipStream_t stream) {
    const float* feat    = (const float*)d_in[0];
    const int*   src     = (const int*)  d_in[1];
    const int*   dst     = (const int*)  d_in[2];
    const float* W_src   = (const float*)d_in[3];
    const float* b_src   = (const float*)d_in[4];
    const float* W_dst   = (const float*)d_in[5];
    const float* b_dst   = (const float*)d_in[6];
    const float* attn    = (const float*)d_in[7];
    const float* out_bias= (const float*)d_in[8];
    const float* fc_W    = (const float*)d_in[9];
    const float* fc_b    = (const float*)d_in[10];
    const float* gamma   = (const float*)d_in[11];
    const float* beta    = (const float*)d_in[12];
    float* z = (float*)d_out;

    char* ws = (char*)d_ws;
    size_t off = 0;
    auto carve = [&](size_t bytes) -> void* {
        void* p = ws + off;
        off = (off + bytes + 255) & ~(size_t)255;
        return p;
    };
    unsigned short* h_src_bf= (unsigned short*)carve((size_t)N_NODES * 256 * 2);
    unsigned short* h_dst_bf= (unsigned short*)carve((size_t)N_NODES * 256 * 2);
    unsigned short* rst_bf  = (unsigned short*)carve((size_t)N_NODES * 256 * 2);
    unsigned short* WtS     = (unsigned short*)carve((size_t)256 * 256 * 2);
    unsigned short* WtD     = (unsigned short*)carve((size_t)256 * 256 * 2);
    unsigned short* WtF     = (unsigned short*)carve((size_t)64 * 256 * 2);
    int*   srcl   = (int*)  carve((size_t)N_EDGES * 4);
    int*   cnt    = (int*)  carve((size_t)2 * N_NODES * 4);
    int*   cursor = cnt + N_NODES;
    int*   offs   = (int*)  carve((size_t)(N_NODES + 1) * 4);
    int*   bsum   = (int*)  carve(128 * 4);
    int*   bpre   = (int*)  carve(128 * 4);
    float* sums   = (float*)carve(128 * 4);
    int*   done   = (int*)  carve(64);

    const int nchunks = (N_NODES + 511) / 512;      // 98

    // prep: weight transposes + zeroing (feat cast fused into proj)
    prep_kernel<<<675, 256, 0, stream>>>(W_src, W_dst, fc_W,
                                         WtS, WtD, WtF, cnt, sums, done);

    // input projections (1 block per tile, fused fp32 cast, 8 phases SxD,
    // swizzled LDS, wide-store epilogue) + fused histogram
    proj_kernel<<<HIST_BLOCKS + NTILES, 256, 0, stream>>>(
        feat, WtS, WtD, b_src, b_dst, h_src_bf, h_dst_bf, dst, cnt);

    // CSR by dst (merged scan -> scatter)
    scan_kernel<<<nchunks, 512, 0, stream>>>(cnt, offs, bsum, bpre, done);
    scatter_kernel<<<(N_EDGES + 255) / 256, 256, 0, stream>>>(src, dst, offs, bpre, cursor, srcl);

    // fused score + softmax + aggregation (1 wave per node, DPP reductions)
    agg_fused_kernel<<<N_NODES / 4, 256, 0, stream>>>(h_src_bf, h_dst_bf, srcl, offs, bpre,
                                                      attn, out_bias, rst_bf);

    // trailing fc + BN partial stats
    fc_bn_kernel<<<(N_NODES + 63) / 64, 256, 0, stream>>>(rst_bf, WtF, fc_b, z, sums, N_NODES);

    // batchnorm finalize + leaky (vectorized)
    bn_final_kernel<<<(N_NODES * 16 + 255) / 256, 256, 0, stream>>>(z, sums, gamma, beta);
}

// Round 9
// 310.496 us; speedup vs baseline: 1.0919x; 1.0036x over previous
//
#include <hip/hip_runtime.h>
#include <math.h>

#define N_NODES 50000
#define N_EDGES 800000
#define HD 256          // NHEAD * OUT_DIM
#define OUT_DIM 64
#define NHEAD 4
#define SLOPE 0.2f
#define BN_EPS 1e-5f
#define LOG2E 1.4426950408889634f
#define NTILES 391      // ceil(N_NODES / 128)
#define HIST_BLOCKS 96

typedef __attribute__((ext_vector_type(8))) short short8;
typedef __attribute__((ext_vector_type(4))) float float4v;

__device__ __forceinline__ float leaky(float x) { return x >= 0.f ? x : SLOPE * x; }

__device__ __forceinline__ float bf2f(unsigned short u) {
    return __uint_as_float(((unsigned)u) << 16);
}
__device__ __forceinline__ unsigned short f2bf(float f) {
    unsigned u = __float_as_uint(f);
    unsigned r = (u + 0x7fffu + ((u >> 16) & 1u)) >> 16;
    return (unsigned short)r;
}

// pack 8 fp32 -> 8 bf16 (RNE, matches prep's cast exactly)
__device__ __forceinline__ short8 pack8(const float4 a, const float4 b) {
    short8 r;
    r[0] = (short)f2bf(a.x); r[1] = (short)f2bf(a.y);
    r[2] = (short)f2bf(a.z); r[3] = (short)f2bf(a.w);
    r[4] = (short)f2bf(b.x); r[5] = (short)f2bf(b.y);
    r[6] = (short)f2bf(b.z); r[7] = (short)f2bf(b.w);
    return r;
}

// DPP rotate-and-add step (builtin form -> compiler schedules/interleaves).
template <int CTRL>
__device__ __forceinline__ float ror_add(float v) {
    const int r = __builtin_amdgcn_update_dpp(0, __float_as_int(v), CTRL, 0xF, 0xF, true);
    return v + __int_as_float(r);
}
// 8-lane-group sum (3 steps): row_half_mirror, quad_perm[2,3,0,1],
// quad_perm[1,0,3,2]. All lanes of each aligned 8-group converge to the sum.
__device__ __forceinline__ float group8_sum(float v) {
    v = ror_add<0x141>(v);   // row_half_mirror: l ^ mirror within 8
    v = ror_add<0x4E>(v);    // quad_perm [2,3,0,1] (xor 2)
    v = ror_add<0xB1>(v);    // quad_perm [1,0,3,2] (xor 1)
    return v;
}

// ---------------------------------------------------------------------------
// prep: 3 weight transpose+casts, zero cnt/cursor/sums/done.
// ---------------------------------------------------------------------------
__global__ __launch_bounds__(256) void prep_kernel(const float* __restrict__ W_src,
                                                   const float* __restrict__ W_dst,
                                                   const float* __restrict__ fc_W,
                                                   unsigned short* __restrict__ WtS,
                                                   unsigned short* __restrict__ WtD,
                                                   unsigned short* __restrict__ WtF,
                                                   int* __restrict__ cnt2,
                                                   float* __restrict__ sums,
                                                   int* __restrict__ done) {
    const int b = blockIdx.x;
    const int t = threadIdx.x;
    if (b < 256) {
        WtS[(size_t)b * 256 + t] = f2bf(W_src[(size_t)t * 256 + b]);
    } else if (b < 512) {
        const int n = b - 256;
        WtD[(size_t)n * 256 + t] = f2bf(W_dst[(size_t)t * 256 + n]);
    } else if (b < 576) {
        const int n = b - 512;
        WtF[(size_t)n * 256 + t] = f2bf(fc_W[(size_t)t * 64 + n]);
    } else if (b < 674) {
        const int i = (b - 576) * 256 + t;
        if (i < 25000) ((int4*)cnt2)[i] = make_int4(0, 0, 0, 0);
    } else {
        if (t < 128) sums[t] = 0.f;
        if (t == 128) done[0] = 0;
    }
}

// ---------------------------------------------------------------------------
// bf16 MFMA GEMM: ONE block per 128-row tile, A loaded fp32 ONCE (fused
// cast), then 8 phases = {S,D} x 4 column chunks, + fused edge histogram.
// ---------------------------------------------------------------------------
__global__ __launch_bounds__(256) void proj_kernel(const float* __restrict__ feat,
                                                   const unsigned short* __restrict__ BtS,
                                                   const unsigned short* __restrict__ BtD,
                                                   const float* __restrict__ bS,
                                                   const float* __restrict__ bD,
                                                   unsigned short* __restrict__ CS,
                                                   unsigned short* __restrict__ CD,
                                                   const int* __restrict__ dst,
                                                   int* __restrict__ cnt) {
    __shared__ unsigned short Bs[64 * 256];   // 32 KB

    if (blockIdx.x < HIST_BLOCKS) {
        for (int i = blockIdx.x * 256 + threadIdx.x; i < N_EDGES; i += HIST_BLOCKS * 256)
            atomicAdd(&cnt[dst[i]], 1);
        return;
    }

    const int tile = blockIdx.x - HIST_BLOCKS;
    if (tile >= NTILES) return;

    const int t    = threadIdx.x;
    const int w    = t >> 6;
    const int lane = t & 63;
    const int q    = lane >> 4;
    const int l16  = lane & 15;

    const int m0 = tile * 128;

    // ---- load A fragments ONCE as fp32, cast in registers (fused cast) ----
    int ar0 = m0 + w * 32 + l16;
    int ar1 = ar0 + 16;
    if (ar0 > N_NODES - 1) ar0 = N_NODES - 1;
    if (ar1 > N_NODES - 1) ar1 = N_NODES - 1;
    const float* Af0 = feat + (size_t)ar0 * 256 + q * 8;
    const float* Af1 = feat + (size_t)ar1 * 256 + q * 8;
    short8 afr0[8], afr1[8];
#pragma unroll
    for (int kk = 0; kk < 8; ++kk) {
        const float4 x0 = *(const float4*)(Af0 + kk * 32);
        const float4 y0 = *(const float4*)(Af0 + kk * 32 + 4);
        const float4 x1 = *(const float4*)(Af1 + kk * 32);
        const float4 y1 = *(const float4*)(Af1 + kk * 32 + 4);
        afr0[kk] = pack8(x0, y0);
        afr1[kk] = pack8(x1, y1);
    }

    // staging thread mapping (constant across phases)
    const int r   = t >> 2;        // B row (= output col within chunk) 0..63
    const int seg = t & 3;
    const int cc  = r >> 4;
    const int L   = r & 15;

    const int la8 = lane * 8;
    const int lsw[4] = {la8, la8 ^ 16, la8 ^ 32, la8 ^ 48};

    for (int ph = 0; ph < 8; ++ph) {
        const bool isD = (ph >= 4);
        const int  c0  = (ph & 3) * 64;
        const unsigned short* Bt   = isD ? BtD : BtS;
        const float*          bias = isD ? bD  : bS;
        unsigned short*       C    = isD ? CD  : CS;

        __syncthreads();   // prior phase's epilogue LDS reads complete
        // ---- stage B chunk, fragment order, XOR-swizzled ----
        {
            const unsigned short* g = Bt + (size_t)(c0 + r) * 256 + seg * 64;
#pragma unroll
            for (int kk2 = 0; kk2 < 2; ++kk2) {
                const int kk   = seg * 2 + kk2;
                const int c8kk = cc * 8 + kk;
                const int key  = ((c8kk >> 1) & 3) << 4;
#pragma unroll
                for (int q2 = 0; q2 < 4; ++q2)
                    *(short8*)(&Bs[((c8kk * 64 + q2 * 16 + L) * 8) ^ key]) =
                        *(const short8*)(g + kk2 * 32 + q2 * 8);
            }
        }
        __syncthreads();

        float vb[4];
#pragma unroll
        for (int c = 0; c < 4; ++c) vb[c] = bias[c0 + c * 16 + l16];

        float4v a0[4] = {}, a1[4] = {};
#pragma unroll
        for (int kk = 0; kk < 8; ++kk) {
            const short8 af0 = afr0[kk];
            const short8 af1 = afr1[kk];
#pragma unroll
            for (int c = 0; c < 4; ++c) {
                const int c8kk = c * 8 + kk;
                const short8 b = *(const short8*)(&Bs[c8kk * 512 + lsw[(c8kk >> 1) & 3]]);
                a0[c] = __builtin_amdgcn_mfma_f32_16x16x32_bf16(af0, b, a0[c], 0, 0, 0);
                a1[c] = __builtin_amdgcn_mfma_f32_16x16x32_bf16(af1, b, a1[c], 0, 0, 0);
            }
        }

        __syncthreads();   // all waves' MFMA B-reads done before Bs reuse
        // ---- transposing epilogue through LDS (per-wave region) ----
        unsigned short* Cw = Bs + w * 2304;    // 32 rows x 64 cols, stride 72
#pragma unroll
        for (int c = 0; c < 4; ++c) {
            const int cl = c * 16 + l16;
#pragma unroll
            for (int i = 0; i < 4; ++i) {
                Cw[(q * 4 + i) * 72 + cl]      = f2bf(a0[c][i] + vb[c]);
                Cw[(q * 4 + i + 16) * 72 + cl] = f2bf(a1[c][i] + vb[c]);
            }
        }
        // per-wave area: wave-local lgkmcnt ordering, no barrier needed here
#pragma unroll
        for (int j = 0; j < 4; ++j) {
            const int rl = j * 8 + (lane >> 3);    // local row 0..31
            const short8 v = *(const short8*)(Cw + rl * 72 + (lane & 7) * 8);
            const int rg = m0 + w * 32 + rl;
            if (rg < N_NODES)
                *(short8*)(&C[(size_t)rg * 256 + c0 + (lane & 7) * 8]) = v;
        }
    }
}

// ---------------------------------------------------------------------------
// fc GEMM (bf16 MFMA, fp32 out) + fused BatchNorm partial-stats epilogue.
// ---------------------------------------------------------------------------
__global__ __launch_bounds__(256) void fc_bn_kernel(const unsigned short* __restrict__ A,
                                                    const unsigned short* __restrict__ Bt,
                                                    const float* __restrict__ bias,
                                                    float* __restrict__ C,
                                                    float* __restrict__ sums,
                                                    int M) {
    const int w    = threadIdx.x >> 6;
    const int lane = threadIdx.x & 63;
    const int q    = lane >> 4;
    const int l16  = lane & 15;
    const int m0   = blockIdx.x * 64;
    const int t    = threadIdx.x;

    __shared__ float ssum[64], ssq[64];
    if (t < 64) { ssum[t] = 0.f; ssq[t] = 0.f; }

    int arow = m0 + w * 16 + l16;
    if (arow > M - 1) arow = M - 1;
    const unsigned short* Ab  = A  + (size_t)arow * 256 + q * 8;
    const unsigned short* Btb = Bt + (size_t)l16 * 256 + q * 8;

    float4v acc[4] = {};

    for (int k0 = 0; k0 < 256; k0 += 32) {
        const short8 af = *(const short8*)(Ab + k0);
#pragma unroll
        for (int c = 0; c < 4; ++c) {
            const short8 bf = *(const short8*)(Btb + (size_t)c * 16 * 256 + k0);
            acc[c] = __builtin_amdgcn_mfma_f32_16x16x32_bf16(af, bf, acc[c], 0, 0, 0);
        }
    }
    __syncthreads();

#pragma unroll
    for (int c = 0; c < 4; ++c) {
        const int col = c * 16 + l16;
        const float b = bias[col];
        float s = 0.f, qq = 0.f;
#pragma unroll
        for (int i = 0; i < 4; ++i) {
            const int r = m0 + w * 16 + q * 4 + i;
            if (r < M) {
                const float v = acc[c][i] + b;
                C[(size_t)r * 64 + col] = v;
                s += v;
                qq += v * v;
            }
        }
        atomicAdd(&ssum[col], s);
        atomicAdd(&ssq[col], qq);
    }
    __syncthreads();
    if (t < 64) {
        atomicAdd(&sums[t], ssum[t]);
        atomicAdd(&sums[64 + t], ssq[t]);
    }
}

// ---------------------------------------------------------------------------
// CSR build: merged 2-level scan (last-block does chunk-sum scan); scatter.
// ---------------------------------------------------------------------------
__global__ __launch_bounds__(512) void scan_kernel(const int* __restrict__ cnt,
                                                   int* __restrict__ offs,
                                                   int* __restrict__ bsum,
                                                   int* __restrict__ bpre,
                                                   int* __restrict__ done) {
    __shared__ int s[512];
    __shared__ bool amLast;
    const int t = threadIdx.x;
    const int i = blockIdx.x * 512 + t;
    const int v = (i < N_NODES) ? cnt[i] : 0;
    s[t] = v;
    __syncthreads();
    for (int off = 1; off < 512; off <<= 1) {
        const int x = (t >= off) ? s[t - off] : 0;
        __syncthreads();
        s[t] += x;
        __syncthreads();
    }
    if (i < N_NODES) offs[i] = s[t] - v;       // exclusive within chunk
    if (t == 511) {
        bsum[blockIdx.x] = s[511];
        __threadfence();
        amLast = (atomicAdd(done, 1) == (int)gridDim.x - 1);
    }
    __syncthreads();
    if (amLast) {
        const int v2 = (t < (int)gridDim.x) ? atomicAdd(&bsum[t], 0) : 0;
        s[t] = v2;
        __syncthreads();
        for (int off = 1; off < 512; off <<= 1) {
            const int x = (t >= off) ? s[t - off] : 0;
            __syncthreads();
            s[t] += x;
            __syncthreads();
        }
        if (t < (int)gridDim.x) bpre[t] = s[t] - v2;
    }
}

__global__ void scatter_kernel(const int* __restrict__ src,
                               const int* __restrict__ dst,
                               const int* __restrict__ offs,
                               const int* __restrict__ bpre,
                               int* __restrict__ cursor,
                               int* __restrict__ srcl) {
    const int i = blockIdx.x * 256 + threadIdx.x;
    if (i < N_EDGES) {
        const int d = dst[i];
        const int p = offs[d] + bpre[d >> 9] + atomicAdd(&cursor[d], 1);
        srcl[p] = src[i];
    }
}

// ---------------------------------------------------------------------------
// Fused GATv2 score + softmax + aggregation: one wave per node, 4 nodes per
// 256-thread block. HALF-WAVE EDGE PAIRING: each 32-lane half processes one
// edge; lane covers 8 dims (uint4 16B gather, half the VMEM instrs); head-dot
// reduces over 8 lanes (3 DPP steps vs 4). Cross-half wsum/acc merged once
// per node via __shfl_xor(.,32). Odd-degree tail = duplicated pair with the
// hi half masked to 0. leaky-dot via free |y| VOP3 modifier; no-max exps.
// ---------------------------------------------------------------------------
__global__ __launch_bounds__(256) void agg_fused_kernel(const unsigned short* __restrict__ h_src,
                                                        const unsigned short* __restrict__ h_dst,
                                                        const int* __restrict__ srcl,
                                                        const int* __restrict__ offs,
                                                        const int* __restrict__ bpre,
                                                        const float* __restrict__ attn,
                                                        const float* __restrict__ out_bias,
                                                        unsigned short* __restrict__ rst) {
    const int node = blockIdx.x * 4 + (threadIdx.x >> 6);
    const int lane = threadIdx.x & 63;
    const int l32  = lane & 31;
    const bool hiH = (lane >= 32);
    const int d8   = l32 * 8;               // first of this lane's 8 dims

    const int beg = offs[node] + bpre[node >> 9];
    const int end = (node + 1 == N_NODES) ? N_EDGES
                                          : (offs[node + 1] + bpre[(node + 1) >> 9]);

    // h_dst slice: 8 dims
    float hd[8];
    {
        const uint4 u = *(const uint4*)(h_dst + (size_t)node * 256 + d8);
        hd[0] = __uint_as_float(u.x << 16); hd[1] = __uint_as_float(u.x & 0xffff0000u);
        hd[2] = __uint_as_float(u.y << 16); hd[3] = __uint_as_float(u.y & 0xffff0000u);
        hd[4] = __uint_as_float(u.z << 16); hd[5] = __uint_as_float(u.z & 0xffff0000u);
        hd[6] = __uint_as_float(u.w << 16); hd[7] = __uint_as_float(u.w & 0xffff0000u);
    }
    float c1[8], c2[8];
    {
        const float4 a0 = *(const float4*)(attn + d8);
        const float4 a1 = *(const float4*)(attn + d8 + 4);
        const float k1 = 0.6f * LOG2E, k2 = 0.4f * LOG2E;
        c1[0] = a0.x * k1; c2[0] = a0.x * k2;
        c1[1] = a0.y * k1; c2[1] = a0.y * k2;
        c1[2] = a0.z * k1; c2[2] = a0.z * k2;
        c1[3] = a0.w * k1; c2[3] = a0.w * k2;
        c1[4] = a1.x * k1; c2[4] = a1.x * k2;
        c1[5] = a1.y * k1; c2[5] = a1.y * k2;
        c1[6] = a1.z * k1; c2[6] = a1.z * k2;
        c1[7] = a1.w * k1; c2[7] = a1.w * k2;
    }

    float wsum = 0.f;
    float acc[8] = {0.f, 0.f, 0.f, 0.f, 0.f, 0.f, 0.f, 0.f};

    // one PAIR of edges (sA -> lo half, sB -> hi half); msk scales wg (tail)
#define EDGE_PAIR(sA, sB, msk)                                                   \
    {                                                                            \
        const int ssel = hiH ? (sB) : (sA);                                      \
        const uint4 u = *(const uint4*)(h_src + (size_t)ssel * 256 + d8);        \
        float r[8];                                                              \
        r[0] = __uint_as_float(u.x << 16); r[1] = __uint_as_float(u.x & 0xffff0000u); \
        r[2] = __uint_as_float(u.y << 16); r[3] = __uint_as_float(u.y & 0xffff0000u); \
        r[4] = __uint_as_float(u.z << 16); r[5] = __uint_as_float(u.z & 0xffff0000u); \
        r[6] = __uint_as_float(u.w << 16); r[7] = __uint_as_float(u.w & 0xffff0000u); \
        float pp = 0.f;                                                          \
        _Pragma("unroll")                                                        \
        for (int j = 0; j < 8; ++j) {                                            \
            const float y = r[j] + hd[j];                                        \
            pp = fmaf(c1[j], y, fmaf(c2[j], __builtin_fabsf(y), pp));            \
        }                                                                        \
        pp = group8_sum(pp);                                                     \
        const float wg = __builtin_amdgcn_exp2f(pp) * (msk);                     \
        wsum += wg;                                                              \
        _Pragma("unroll")                                                        \
        for (int j = 0; j < 8; ++j) acc[j] = fmaf(wg, r[j], acc[j]);             \
    }

    int p = beg;
    const int npairs = (end - beg) >> 1;
    const int nf4 = npairs >> 2;            // 4 pairs = 8 edges per iteration
    for (int it = 0; it < nf4; ++it, p += 8) {
        const int s0 = __builtin_amdgcn_readfirstlane(srcl[p]);
        const int s1 = __builtin_amdgcn_readfirstlane(srcl[p + 1]);
        const int s2 = __builtin_amdgcn_readfirstlane(srcl[p + 2]);
        const int s3 = __builtin_amdgcn_readfirstlane(srcl[p + 3]);
        const int s4 = __builtin_amdgcn_readfirstlane(srcl[p + 4]);
        const int s5 = __builtin_amdgcn_readfirstlane(srcl[p + 5]);
        const int s6 = __builtin_amdgcn_readfirstlane(srcl[p + 6]);
        const int s7 = __builtin_amdgcn_readfirstlane(srcl[p + 7]);
        EDGE_PAIR(s0, s1, 1.f);
        EDGE_PAIR(s2, s3, 1.f);
        EDGE_PAIR(s4, s5, 1.f);
        EDGE_PAIR(s6, s7, 1.f);
    }
    for (int rp = nf4 * 4; rp < npairs; ++rp, p += 2) {
        const int s0 = __builtin_amdgcn_readfirstlane(srcl[p]);
        const int s1 = __builtin_amdgcn_readfirstlane(srcl[p + 1]);
        EDGE_PAIR(s0, s1, 1.f);
    }
    if ((end - beg) & 1) {
        const float hm = hiH ? 0.f : 1.f;
        const int s0 = __builtin_amdgcn_readfirstlane(srcl[p]);
        EDGE_PAIR(s0, s0, hm);
    }
#undef EDGE_PAIR

    // merge the two half-waves (once per node)
    wsum += __shfl_xor(wsum, 32, 64);
#pragma unroll
    for (int j = 0; j < 8; ++j) acc[j] += __shfl_xor(acc[j], 32, 64);

    const float inv = (wsum > 0.f) ? 1.f / wsum : 0.f;
    if (!hiH) {
        const float4 ob0 = *(const float4*)(out_bias + d8);
        const float4 ob1 = *(const float4*)(out_bias + d8 + 4);
        short8 o;
        o[0] = (short)f2bf(fmaf(acc[0], inv, ob0.x));
        o[1] = (short)f2bf(fmaf(acc[1], inv, ob0.y));
        o[2] = (short)f2bf(fmaf(acc[2], inv, ob0.z));
        o[3] = (short)f2bf(fmaf(acc[3], inv, ob0.w));
        o[4] = (short)f2bf(fmaf(acc[4], inv, ob1.x));
        o[5] = (short)f2bf(fmaf(acc[5], inv, ob1.y));
        o[6] = (short)f2bf(fmaf(acc[6], inv, ob1.z));
        o[7] = (short)f2bf(fmaf(acc[7], inv, ob1.w));
        *(short8*)(&rst[(size_t)node * 256 + d8]) = o;
    }
}

// ---------------------------------------------------------------------------
// BatchNorm finalize + LeakyReLU (float4-vectorized streaming pass)
// ---------------------------------------------------------------------------
__global__ __launch_bounds__(256) void bn_final_kernel(float* __restrict__ z,
                                                       const float* __restrict__ sums,
                                                       const float* __restrict__ gamma,
                                                       const float* __restrict__ beta) {
    const int i = blockIdx.x * 256 + threadIdx.x;    // index of a float4 group
    if (i < N_NODES * 16) {
        const int c4 = (i & 15) * 4;                 // column of first component
        float4 v = ((const float4*)z)[i];
        float out[4] = {v.x, v.y, v.z, v.w};
#pragma unroll
        for (int j = 0; j < 4; ++j) {
            const int col = c4 + j;
            const float mu  = sums[col] * (1.f / N_NODES);
            const float var = sums[64 + col] * (1.f / N_NODES) - mu * mu;
            const float sc  = rsqrtf(var + BN_EPS) * gamma[col];
            const float sh  = beta[col] - mu * sc;
            out[j] = leaky(fmaf(out[j], sc, sh));
        }
        ((float4*)z)[i] = make_float4(out[0], out[1], out[2], out[3]);
    }
}

// ---------------------------------------------------------------------------
extern "C" void kernel_launch(void* const* d_in, const int* in_sizes, int n_in,
                              void* d_out, int out_size, void* d_ws, size_t ws_size,
                              hipStream_t stream) {
    const float* feat    = (const float*)d_in[0];
    const int*   src     = (const int*)  d_in[1];
    const int*   dst     = (const int*)  d_in[2];
    const float* W_src   = (const float*)d_in[3];
    const float* b_src   = (const float*)d_in[4];
    const float* W_dst   = (const float*)d_in[5];
    const float* b_dst   = (const float*)d_in[6];
    const float* attn    = (const float*)d_in[7];
    const float* out_bias= (const float*)d_in[8];
    const float* fc_W    = (const float*)d_in[9];
    const float* fc_b    = (const float*)d_in[10];
    const float* gamma   = (const float*)d_in[11];
    const float* beta    = (const float*)d_in[12];
    float* z = (float*)d_out;

    char* ws = (char*)d_ws;
    size_t off = 0;
    auto carve = [&](size_t bytes) -> void* {
        void* p = ws + off;
        off = (off + bytes + 255) & ~(size_t)255;
        return p;
    };
    unsigned short* h_src_bf= (unsigned short*)carve((size_t)N_NODES * 256 * 2);
    unsigned short* h_dst_bf= (unsigned short*)carve((size_t)N_NODES * 256 * 2);
    unsigned short* rst_bf  = (unsigned short*)carve((size_t)N_NODES * 256 * 2);
    unsigned short* WtS     = (unsigned short*)carve((size_t)256 * 256 * 2);
    unsigned short* WtD     = (unsigned short*)carve((size_t)256 * 256 * 2);
    unsigned short* WtF     = (unsigned short*)carve((size_t)64 * 256 * 2);
    int*   srcl   = (int*)  carve((size_t)N_EDGES * 4);
    int*   cnt    = (int*)  carve((size_t)2 * N_NODES * 4);
    int*   cursor = cnt + N_NODES;
    int*   offs   = (int*)  carve((size_t)(N_NODES + 1) * 4);
    int*   bsum   = (int*)  carve(128 * 4);
    int*   bpre   = (int*)  carve(128 * 4);
    float* sums   = (float*)carve(128 * 4);
    int*   done   = (int*)  carve(64);

    const int nchunks = (N_NODES + 511) / 512;      // 98

    // prep: weight transposes + zeroing (feat cast fused into proj)
    prep_kernel<<<675, 256, 0, stream>>>(W_src, W_dst, fc_W,
                                         WtS, WtD, WtF, cnt, sums, done);

    // input projections (1 block per tile, fused fp32 cast, 8 phases SxD,
    // swizzled LDS, wide-store epilogue) + fused histogram
    proj_kernel<<<HIST_BLOCKS + NTILES, 256, 0, stream>>>(
        feat, WtS, WtD, b_src, b_dst, h_src_bf, h_dst_bf, dst, cnt);

    // CSR by dst (merged scan -> scatter)
    scan_kernel<<<nchunks, 512, 0, stream>>>(cnt, offs, bsum, bpre, done);
    scatter_kernel<<<(N_EDGES + 255) / 256, 256, 0, stream>>>(src, dst, offs, bpre, cursor, srcl);

    // fused score + softmax + aggregation (half-wave edge pairing)
    agg_fused_kernel<<<N_NODES / 4, 256, 0, stream>>>(h_src_bf, h_dst_bf, srcl, offs, bpre,
                                                      attn, out_bias, rst_bf);

    // trailing fc + BN partial stats
    fc_bn_kernel<<<(N_NODES + 63) / 64, 256, 0, stream>>>(rst_bf, WtF, fc_b, z, sums, N_NODES);

    // batchnorm finalize + leaky (vectorized)
    bn_final_kernel<<<(N_NODES * 16 + 255) / 256, 256, 0, stream>>>(z, sums, gamma, beta);
}